// Round 1
// 799.512 us; speedup vs baseline: 1.0033x; 1.0033x over previous
//
#include <hip/hip_runtime.h>
#include <hip/hip_fp16.h>

typedef unsigned int uint32;
typedef _Float16 f16;
typedef f16 f16x8 __attribute__((ext_vector_type(8)));
typedef float f32x4 __attribute__((ext_vector_type(4)));

__device__ __forceinline__ float h2f(__half v) { return __half2float(v); }
__device__ __forceinline__ __half f2h(float v) { return __float2half(v); }

// ---------------------------------------------------------------------------
// K1: t1 = leaky_relu(x @ conv1_w + conv1_b)  (131072,180)->(131072,36) f16
// ---------------------------------------------------------------------------
__global__ __launch_bounds__(256) void k1_conv1(const float* __restrict__ X,
                                                const float* __restrict__ W1,
                                                const float* __restrict__ B1,
                                                __half* __restrict__ T1) {
  __shared__ float sm[60 * 132 + 60 * 36];
  float* Xt = sm;              // [60][132] (128 + pad4), k-major
  float* Ws = sm + 60 * 132;   // [60][36]
  int t = threadIdx.x;
  int p0 = blockIdx.x * 128;
  bool act = t < 144;
  int r0 = (t / 9) * 4, c0 = (t % 9) * 4;
  float acc[2][16];
#pragma unroll
  for (int h = 0; h < 2; ++h)
#pragma unroll
    for (int i = 0; i < 16; ++i) acc[h][i] = 0.f;

  for (int chunk = 0; chunk < 3; ++chunk) {
    __syncthreads();
    int kc = chunk * 60;
    for (int i = t; i < 128 * 60; i += 256) {
      int m = i / 60, k = i % 60;
      Xt[k * 132 + m] = X[(size_t)(p0 + m) * 180 + kc + k];
    }
    for (int i = t; i < 60 * 36; i += 256) {
      int k = i / 36, c = i % 36;
      Ws[k * 36 + c] = W1[(kc + k) * 36 + c];
    }
    __syncthreads();
    if (act) {
      for (int k = 0; k < 60; ++k) {
        float4 a0 = *(const float4*)&Xt[k * 132 + r0];
        float4 a1 = *(const float4*)&Xt[k * 132 + r0 + 64];
        float4 b  = *(const float4*)&Ws[k * 36 + c0];
        float av0[4] = {a0.x, a0.y, a0.z, a0.w};
        float av1[4] = {a1.x, a1.y, a1.z, a1.w};
        float bv[4]  = {b.x, b.y, b.z, b.w};
#pragma unroll
        for (int i = 0; i < 4; ++i)
#pragma unroll
          for (int j = 0; j < 4; ++j) {
            acc[0][i * 4 + j] += av0[i] * bv[j];
            acc[1][i * 4 + j] += av1[i] * bv[j];
          }
      }
    }
  }
  if (!act) return;
  float bb[4];
#pragma unroll
  for (int i = 0; i < 4; ++i) bb[i] = B1[c0 + i];
#pragma unroll
  for (int h = 0; h < 2; ++h)
#pragma unroll
    for (int ri = 0; ri < 4; ++ri) {
      int p = p0 + h * 64 + r0 + ri;
      __half* o = T1 + (size_t)p * 36 + c0;
      __half2 h01, h23;
      float v0 = acc[h][ri * 4 + 0] + bb[0];
      float v1 = acc[h][ri * 4 + 1] + bb[1];
      float v2 = acc[h][ri * 4 + 2] + bb[2];
      float v3 = acc[h][ri * 4 + 3] + bb[3];
      h01.x = f2h(v0 > 0.f ? v0 : 0.2f * v0);
      h01.y = f2h(v1 > 0.f ? v1 : 0.2f * v1);
      h23.x = f2h(v2 > 0.f ? v2 : 0.2f * v2);
      h23.y = f2h(v3 > 0.f ? v3 : 0.2f * v3);
      *(__half2*)o = h01;
      *(__half2*)(o + 2) = h23;
    }
}

// ---------------------------------------------------------------------------
// K2: t2 = leaky_relu(conv3x3(t1) + conv2_b), SAME. 64 px x 36 co tile.
// ---------------------------------------------------------------------------
__global__ __launch_bounds__(256) void k2_conv2(const __half* __restrict__ T1,
                                                const float* __restrict__ W2,
                                                const float* __restrict__ B2,
                                                __half* __restrict__ T2) {
  __shared__ float ins[3 * 68 * 37];   // [kh][xx][ci], stride 37
  __shared__ float ws2[9 * 36 * 36];   // [kh*3+kw][ci][co]
  int t = threadIdx.x;
  int p0 = blockIdx.x * 64;
  int b = p0 >> 16, y = (p0 >> 8) & 255, x0 = p0 & 255;
  for (int i = t; i < 11664; i += 256) ws2[i] = W2[i];
  for (int i = t; i < 3 * 66 * 36; i += 256) {
    int kh = i / 2376, rem = i % 2376;
    int xx = rem / 36, ci = rem % 36;
    int ry = y + kh - 1, gx = x0 + xx - 1;
    float v = 0.f;
    if ((unsigned)ry < 256u && (unsigned)gx < 256u)
      v = h2f(T1[((size_t)(b * 256 + ry) * 256 + gx) * 36 + ci]);
    ins[kh * 2516 + xx * 37 + ci] = v;
  }
  __syncthreads();
  bool act = t < 144;
  if (!act) return;
  int pl = (t / 9) * 4, c0 = (t % 9) * 4;
  float acc[16];
#pragma unroll
  for (int i = 0; i < 16; ++i) acc[i] = 0.f;
  for (int kh = 0; kh < 3; ++kh) {
    const float* base = ins + kh * 2516;
    for (int ci = 0; ci < 36; ++ci) {
      float rv[6];
#pragma unroll
      for (int u = 0; u < 6; ++u) rv[u] = base[(pl + u) * 37 + ci];
#pragma unroll
      for (int kw = 0; kw < 3; ++kw) {
        float4 w = *(const float4*)&ws2[((kh * 3 + kw) * 36 + ci) * 36 + c0];
        float wv[4] = {w.x, w.y, w.z, w.w};
#pragma unroll
        for (int jj = 0; jj < 4; ++jj)
#pragma unroll
          for (int i2 = 0; i2 < 4; ++i2)
            acc[jj * 4 + i2] += rv[jj + kw] * wv[i2];
      }
    }
  }
  float bb[4];
#pragma unroll
  for (int i = 0; i < 4; ++i) bb[i] = B2[c0 + i];
#pragma unroll
  for (int jj = 0; jj < 4; ++jj) {
    int p = p0 + pl + jj;
    __half* o = T2 + (size_t)p * 36 + c0;
    float v0 = acc[jj * 4 + 0] + bb[0];
    float v1 = acc[jj * 4 + 1] + bb[1];
    float v2 = acc[jj * 4 + 2] + bb[2];
    float v3 = acc[jj * 4 + 3] + bb[3];
    __half2 h01, h23;
    h01.x = f2h(v0 > 0.f ? v0 : 0.2f * v0);
    h01.y = f2h(v1 > 0.f ? v1 : 0.2f * v1);
    h23.x = f2h(v2 > 0.f ? v2 : 0.2f * v2);
    h23.y = f2h(v3 > 0.f ? v3 : 0.2f * v3);
    *(__half2*)o = h01;
    *(__half2*)(o + 2) = h23;
  }
}

// ---------------------------------------------------------------------------
// K3 (MFMA): qv = (t2 @ conv3_w + b3) * (x @ dfe_lin_w + bd), stored x64 f16
// windowed. Persistent-A restructure: each block owns 128 rows and computes
// ALL 180 output cols. X tile (f16, K padded to 192) and T2 tile (K padded
// to 40) staged to LDS ONCE; inner loop over bn=0..3 x K-chunks stages only
// the 48x32 weight chunk (L2-resident). X/T2 are fetched from HBM exactly
// once (was 4x -> 275 MB FETCH; now ~110 MB).
// Grid: 1024 blocks (one per 128-row panel).
// ---------------------------------------------------------------------------
__global__ __launch_bounds__(256) void k3_qv(const float* __restrict__ X,
                                             const __half* __restrict__ T2,
                                             const float* __restrict__ W3,
                                             const float* __restrict__ B3,
                                             const float* __restrict__ WD,
                                             const float* __restrict__ BD,
                                             __half* __restrict__ QX) {
  __shared__ f16 Ax[128 * 192];  // X tile, K=180 zero-padded to 192
  __shared__ f16 At[128 * 40];   // T2 tile, K=36 zero-padded to 40
  __shared__ f16 Bs[48 * 40];    // weight chunk, n-major
  int t = threadIdx.x;
  int p0 = blockIdx.x * 128;
  int lane = t & 63, wave = t >> 6;
  int lm = lane & 15, lq = lane >> 4;

  // ---- stage T2 tile once (uint2 = 4 f16) ----
  for (int i = t; i < 1280; i += 256) {
    int m = i / 10, kq = (i % 10) * 4;
    uint2 val = {0u, 0u};
    if (kq < 36) val = *(const uint2*)&T2[(size_t)(p0 + m) * 36 + kq];
    *(uint2*)&At[m * 40 + kq] = val;
  }
  // ---- stage X tile once, f32 -> f16 ----
  for (int i = t; i < 6144; i += 256) {
    int m = i / 48, kq = (i % 48) * 4;
    union { f16 h[4]; uint2 u; } val;
    val.u.x = 0u; val.u.y = 0u;
    if (kq < 180) {
      float4 x = *(const float4*)&X[(size_t)(p0 + m) * 180 + kq];
      val.h[0] = (f16)x.x; val.h[1] = (f16)x.y;
      val.h[2] = (f16)x.z; val.h[3] = (f16)x.w;
    }
    *(uint2*)&Ax[m * 192 + kq] = val.u;
  }

  for (int bn = 0; bn < 4; ++bn) {
    int n0 = bn * 48;
    f32x4 accC[2][3], accD[2][3];
#pragma unroll
    for (int i = 0; i < 2; ++i)
#pragma unroll
      for (int j = 0; j < 3; ++j) {
        accC[i][j] = (f32x4){0.f, 0.f, 0.f, 0.f};
        accD[i][j] = (f32x4){0.f, 0.f, 0.f, 0.f};
      }

    // ---- phase 1: accC = T2 @ W3 (K=36, chunks of 32) ----
    for (int ch = 0; ch < 2; ++ch) {
      int kc = ch * 32;
      __syncthreads();  // protects Bs (prev readers done) + first-iter A-stage
      for (int i = t; i < 384; i += 256) {
        int k = i / 12, nq = (i % 12) * 4;
        float4 w = {0.f, 0.f, 0.f, 0.f};
        int kk = kc + k;
        if (kk < 36 && n0 + nq < 180)
          w = *(const float4*)&W3[(size_t)kk * 180 + n0 + nq];
        Bs[(nq + 0) * 40 + k] = (f16)w.x;
        Bs[(nq + 1) * 40 + k] = (f16)w.y;
        Bs[(nq + 2) * 40 + k] = (f16)w.z;
        Bs[(nq + 3) * 40 + k] = (f16)w.w;
      }
      __syncthreads();
      f16x8 af[2], bf[3];
#pragma unroll
      for (int mt = 0; mt < 2; ++mt) {
        int row = wave * 32 + mt * 16 + lm;
        if (ch == 0) {
          af[mt] = *(const f16x8*)&At[row * 40 + lq * 8];
        } else {
          // chunk k=32..63: only lq==0 has real data (k 32..39, 36..39 zero);
          // lanes lq>=1 -> k>=40 which is zero on the B side too.
          f16x8 z = {(f16)0, (f16)0, (f16)0, (f16)0, (f16)0, (f16)0, (f16)0, (f16)0};
          af[mt] = (lq == 0) ? *(const f16x8*)&At[row * 40 + 32] : z;
        }
      }
#pragma unroll
      for (int nt = 0; nt < 3; ++nt)
        bf[nt] = *(const f16x8*)&Bs[(nt * 16 + lm) * 40 + lq * 8];
#pragma unroll
      for (int mt = 0; mt < 2; ++mt)
#pragma unroll
        for (int nt = 0; nt < 3; ++nt)
          accC[mt][nt] = __builtin_amdgcn_mfma_f32_16x16x32_f16(
              af[mt], bf[nt], accC[mt][nt], 0, 0, 0);
    }

    // ---- phase 2: accD = X @ WD (K=180, 6 chunks of 32) ----
    for (int ch = 0; ch < 6; ++ch) {
      int kc = ch * 32;
      __syncthreads();
      for (int i = t; i < 384; i += 256) {
        int k = i / 12, nq = (i % 12) * 4;
        float4 w = {0.f, 0.f, 0.f, 0.f};
        int kk = kc + k;
        if (kk < 180 && n0 + nq < 180)
          w = *(const float4*)&WD[(size_t)kk * 180 + n0 + nq];
        Bs[(nq + 0) * 40 + k] = (f16)w.x;
        Bs[(nq + 1) * 40 + k] = (f16)w.y;
        Bs[(nq + 2) * 40 + k] = (f16)w.z;
        Bs[(nq + 3) * 40 + k] = (f16)w.w;
      }
      __syncthreads();
      f16x8 af[2], bf[3];
#pragma unroll
      for (int mt = 0; mt < 2; ++mt) {
        int row = wave * 32 + mt * 16 + lm;
        af[mt] = *(const f16x8*)&Ax[row * 192 + kc + lq * 8];
      }
#pragma unroll
      for (int nt = 0; nt < 3; ++nt)
        bf[nt] = *(const f16x8*)&Bs[(nt * 16 + lm) * 40 + lq * 8];
#pragma unroll
      for (int mt = 0; mt < 2; ++mt)
#pragma unroll
        for (int nt = 0; nt < 3; ++nt)
          accD[mt][nt] = __builtin_amdgcn_mfma_f32_16x16x32_f16(
              af[mt], bf[nt], accD[mt][nt], 0, 0, 0);
    }

    // ---- epilogue: qv = (accC+b3)*(accD+bd)*64, windowed f16 scatter ----
    float cb[3], db[3];
#pragma unroll
    for (int nt = 0; nt < 3; ++nt) {
      int col = n0 + nt * 16 + lm;
      cb[nt] = (col < 180) ? B3[col] : 0.f;
      db[nt] = (col < 180) ? BD[col] : 0.f;
    }
#pragma unroll
    for (int mt = 0; mt < 2; ++mt) {
#pragma unroll
      for (int reg = 0; reg < 4; ++reg) {
        int p = p0 + wave * 32 + mt * 16 + lq * 4 + reg;
        int b = p >> 16, y = (p >> 8) & 255, x = p & 255;
        int wi = (b << 8) | ((y >> 4) << 4) | (x >> 4);
        int l = ((y & 15) << 4) | (x & 15);
        __half* orow = QX + ((size_t)(wi * 256 + l)) * 180;
#pragma unroll
        for (int nt = 0; nt < 3; ++nt) {
          int col = n0 + nt * 16 + lm;
          if (col < 180)
            orow[col] = f2h((accC[mt][nt][reg] + cb[nt]) *
                            (accD[mt][nt][reg] + db[nt]) * 64.f);
        }
      }
    }
  }
}

// ---------------------------------------------------------------------------
// K5a: position-bias MLP over 961 grid points -> PTAB[961][6] f32
// ---------------------------------------------------------------------------
__device__ __forceinline__ void ln_relu11(const float* p, const float* g,
                                          const float* b, float* r) {
  float m = 0.f;
#pragma unroll
  for (int j = 0; j < 11; ++j) m += p[j];
  m *= (1.0f / 11.0f);
  float v = 0.f;
#pragma unroll
  for (int j = 0; j < 11; ++j) { float d = p[j] - m; v += d * d; }
  v *= (1.0f / 11.0f);
  float inv = 1.0f / sqrtf(v + 1e-5f);
#pragma unroll
  for (int j = 0; j < 11; ++j) {
    float xn = (p[j] - m) * inv * g[j] + b[j];
    r[j] = fmaxf(xn, 0.f);
  }
}
__device__ __forceinline__ void mm11(const float* r, const float* W,
                                     const float* b, float* o) {
#pragma unroll
  for (int j2 = 0; j2 < 11; ++j2) {
    float s = b[j2];
#pragma unroll
    for (int j = 0; j < 11; ++j) s += r[j] * W[j * 11 + j2];
    o[j2] = s;
  }
}

__global__ __launch_bounds__(256) void k5a_posmlp(
    const float* PPW, const float* PPB,
    const float* LN1G, const float* LN1B, const float* M1W, const float* M1B,
    const float* LN2G, const float* LN2B, const float* M2W, const float* M2B,
    const float* LN3G, const float* LN3B, const float* M3W, const float* M3B,
    float* __restrict__ PTAB) {
  int t = blockIdx.x * 256 + threadIdx.x;
  if (t >= 961) return;
  float g0 = (float)(t / 31) - 15.0f;
  float g1 = (float)(t % 31) - 15.0f;
  float p[11], r[11];
#pragma unroll
  for (int j = 0; j < 11; ++j)
    p[j] = g0 * PPW[j] + g1 * PPW[11 + j] + PPB[j];
  ln_relu11(p, LN1G, LN1B, r);
  mm11(r, M1W, M1B, p);
  ln_relu11(p, LN2G, LN2B, r);
  mm11(r, M2W, M2B, p);
  ln_relu11(p, LN3G, LN3B, r);
#pragma unroll
  for (int h = 0; h < 6; ++h) {
    float s = M3B[h];
#pragma unroll
    for (int j = 0; j < 11; ++j) s += r[j] * M3W[j * 6 + h];
    PTAB[t * 6 + h] = s;
  }
}

// ---------------------------------------------------------------------------
// K5b: RPB[h][l][m] = mean over 2x2 of PTAB[(dr+15)*31+(dc+15)][h]
// ---------------------------------------------------------------------------
__global__ __launch_bounds__(256) void k5b_rpb(const float* __restrict__ PTAB,
                                               float* __restrict__ RPB) {
  int t = blockIdx.x * 256 + threadIdx.x;  // < 98304
  int m = t & 63;
  int l = (t >> 6) & 255;
  int h = t >> 14;
  int mh = m >> 3, mw = m & 7;
  int qr = l >> 4, qc = l & 15;
  float s = 0.f;
#pragma unroll
  for (int rh = 0; rh < 2; ++rh)
#pragma unroll
    for (int rw = 0; rw < 2; ++rw) {
      int dr = qr - (mh * 2 + rh) + 15;
      int dc = qc - (mw * 2 + rw) + 15;
      s += PTAB[(dr * 31 + dc) * 6 + h];
    }
  RPB[t] = 0.25f * s;
}

// ---------------------------------------------------------------------------
// K7a: cc[wi][c][d] = sum_l q[l][c]*v[l][d] / 256, f32 out (true scale).
// ---------------------------------------------------------------------------
__global__ __launch_bounds__(256) void k7a_cc(const __half* __restrict__ QX,
                                              float* __restrict__ CC) {
  __shared__ __half qs[64 * 90];
  __shared__ __half vs[64 * 90];
  int wi = blockIdx.x, t = threadIdx.x;
  int c0 = (t % 15) * 6, d0 = (t / 15) * 6;
  bool act = t < 225;
  float acc[36];
#pragma unroll
  for (int i = 0; i < 36; ++i) acc[i] = 0.f;
  const uint32* G = (const uint32*)(QX + (size_t)wi * 46080);
  uint32* qsw = (uint32*)qs;
  uint32* vsw = (uint32*)vs;
  for (int pass = 0; pass < 4; ++pass) {
    __syncthreads();
    for (int i = t; i < 2880; i += 256) {
      int l = i / 45, k = i % 45;
      int gw = (pass * 64 + l) * 90;
      qsw[l * 45 + k] = G[gw + k];
      vsw[l * 45 + k] = G[gw + 45 + k];
    }
    __syncthreads();
    if (act) {
      for (int l = 0; l < 64; ++l) {
        const __half2* qh = (const __half2*)&qs[l * 90 + c0];
        const __half2* vh = (const __half2*)&vs[l * 90 + d0];
        float a[6], b[6];
#pragma unroll
        for (int k = 0; k < 3; ++k) {
          __half2 x = qh[k];
          a[2 * k] = __low2float(x); a[2 * k + 1] = __high2float(x);
          __half2 y = vh[k];
          b[2 * k] = __low2float(y); b[2 * k + 1] = __high2float(y);
        }
#pragma unroll
        for (int i = 0; i < 6; ++i)
#pragma unroll
          for (int j = 0; j < 6; ++j) acc[i * 6 + j] += a[i] * b[j];
      }
    }
  }
  if (act) {
    const float s = 1.0f / (256.0f * 4096.0f);
#pragma unroll
    for (int i = 0; i < 6; ++i)
#pragma unroll
      for (int j = 0; j < 6; ++j)
        CC[((size_t)(wi * 90 + c0 + i)) * 90 + d0 + j] = acc[i * 6 + j] * s;
  }
}

// ---------------------------------------------------------------------------
// KA: per window: vp (LDS, x256) from v(x64); corr = q.vp/15 + rpb;
// x_sp written IN PLACE over q-channels as 8192*x_sp (f16).
// ---------------------------------------------------------------------------
__global__ __launch_bounds__(256) void kA_xsp(__half* __restrict__ QX,
                                              const float* __restrict__ RPB,
                                              const float* __restrict__ SLW,
                                              const float* __restrict__ SLB) {
  __shared__ __half vlds[256 * 90];
  __shared__ __half vpT[6 * 15 * 64];
  int wi = blockIdx.x, t = threadIdx.x;
  __half* QW = QX + (size_t)wi * 46080;
  const uint32* G = (const uint32*)QW;
  uint32* VW = (uint32*)vlds;
  for (int i = t; i < 11520; i += 256) {
    int l = i / 45, k = i % 45;
    VW[l * 45 + k] = G[l * 90 + 45 + k];
  }
  __syncthreads();
  float w0 = SLW[0], w1 = SLW[1], w2 = SLW[2], w3 = SLW[3];
  float sb = SLB[0];
  for (int e = t; e < 5760; e += 256) {
    int m = e & 63, c = (e >> 6) % 15, h = e / 960;
    int mh = m >> 3, mw = m & 7, lb = mh * 32 + mw * 2;
    int ch = h * 15 + c;
    float s = w0 * h2f(vlds[lb * 90 + ch]) + w1 * h2f(vlds[(lb + 1) * 90 + ch])
            + w2 * h2f(vlds[(lb + 16) * 90 + ch]) + w3 * h2f(vlds[(lb + 17) * 90 + ch]);
    vpT[ch * 64 + m] = f2h(s * 4.f + sb * 256.f);
  }
  __syncthreads();
  int l = t;
  for (int h = 0; h < 6; ++h) {
    __half* qrow = QW + l * 180 + h * 15;
    float qreg[15];
#pragma unroll
    for (int c = 0; c < 15; ++c) qreg[c] = h2f(qrow[c]);
    float corr[64];
#pragma unroll
    for (int m = 0; m < 64; ++m) corr[m] = 0.f;
    for (int c = 0; c < 15; ++c) {
      float qc = qreg[c];
      const __half2* vp2 = (const __half2*)&vpT[(h * 15 + c) * 64];
#pragma unroll
      for (int m2 = 0; m2 < 32; ++m2) {
        __half2 vv = vp2[m2];
        corr[2 * m2]     += qc * __low2float(vv);
        corr[2 * m2 + 1] += qc * __high2float(vv);
      }
    }
    const float4* rb4 = (const float4*)(RPB + ((size_t)(h * 256 + l)) * 64);
    const float inv = 1.0f / (15.0f * 64.0f * 256.0f);
#pragma unroll
    for (int m4 = 0; m4 < 16; ++m4) {
      float4 rv = rb4[m4];
      corr[4 * m4 + 0] = corr[4 * m4 + 0] * inv + rv.x;
      corr[4 * m4 + 1] = corr[4 * m4 + 1] * inv + rv.y;
      corr[4 * m4 + 2] = corr[4 * m4 + 2] * inv + rv.z;
      corr[4 * m4 + 3] = corr[4 * m4 + 3] * inv + rv.w;
    }
    for (int c = 0; c < 15; ++c) {
      const __half2* vp2 = (const __half2*)&vpT[(h * 15 + c) * 64];
      float s = 0.f;
#pragma unroll
      for (int m2 = 0; m2 < 32; ++m2) {
        __half2 vv = vp2[m2];
        s += corr[2 * m2] * __low2float(vv) + corr[2 * m2 + 1] * __high2float(vv);
      }
      qrow[c] = f2h(s * 32.f);  // 256*x_sp * 32 = 8192*x_sp
    }
  }
}

// ---------------------------------------------------------------------------
// KB: per window: x_ch[l][c] = sum_d cc[c][d]*v[l][d], written IN PLACE over
// v-channels as 8192*x_ch (f16).
// ---------------------------------------------------------------------------
__global__ __launch_bounds__(256) void kB_xch(__half* __restrict__ QX,
                                              const float* __restrict__ CC) {
  __shared__ __half vlds[256 * 90];
  __shared__ __half ccs[90 * 90];    // scaled x65536
  int wi = blockIdx.x, t = threadIdx.x;
  __half* QW = QX + (size_t)wi * 46080;
  const uint32* G = (const uint32*)QW;
  uint32* VW = (uint32*)vlds;
  for (int i = t; i < 11520; i += 256) {
    int l = i / 45, k = i % 45;
    VW[l * 45 + k] = G[l * 90 + 45 + k];
  }
  const float* ccg = CC + (size_t)wi * 8100;
  for (int i = t; i < 8100; i += 256) ccs[i] = f2h(ccg[i] * 65536.f);
  __syncthreads();
  int l = t;
  float vr[90];
  const __half2* v2 = (const __half2*)&vlds[l * 90];
#pragma unroll
  for (int k = 0; k < 45; ++k) {
    __half2 h = v2[k];
    vr[2 * k] = __low2float(h); vr[2 * k + 1] = __high2float(h);
  }
  __half* orow = QW + l * 180 + 90;
  for (int c = 0; c < 90; ++c) {
    const __half2* cr = (const __half2*)&ccs[c * 90];
    float s = 0.f;
#pragma unroll
    for (int k = 0; k < 45; ++k) {
      __half2 h = cr[k];
      s += vr[2 * k] * __low2float(h) + vr[2 * k + 1] * __high2float(h);
    }
    // s = 2^22 * x_ch ; store 2^13 * x_ch
    orow[c] = f2h(s * 0.001953125f);
  }
}

// ---------------------------------------------------------------------------
// K8 (MFMA): out = (XS/8192) @ proj_w + proj_b, f32 out, window-reverse
// scatter. Persistent-A restructure (same as k3): XS tile staged once
// (K=180 padded to 192), loop bn=0..3 over 48-col weight chunks.
// Grid: 1024 blocks.
// ---------------------------------------------------------------------------
__global__ __launch_bounds__(256) void k8_proj(const __half* __restrict__ XS,
                                               const float* __restrict__ PW,
                                               const float* __restrict__ PB,
                                               float* __restrict__ OUT) {
  __shared__ f16 Ax[128 * 192];
  __shared__ f16 Bs[48 * 40];
  int t = threadIdx.x;
  int w0r = blockIdx.x * 128;
  int lane = t & 63, wave = t >> 6;
  int lm = lane & 15, lq = lane >> 4;

  // ---- stage XS tile once (already f16; uint2 = 4 f16) ----
  for (int i = t; i < 6144; i += 256) {
    int m = i / 48, kq = (i % 48) * 4;
    uint2 val = {0u, 0u};
    if (kq < 180) val = *(const uint2*)&XS[(size_t)(w0r + m) * 180 + kq];
    *(uint2*)&Ax[m * 192 + kq] = val;
  }

  for (int bn = 0; bn < 4; ++bn) {
    int n0 = bn * 48;
    f32x4 acc[2][3];
#pragma unroll
    for (int i = 0; i < 2; ++i)
#pragma unroll
      for (int j = 0; j < 3; ++j) acc[i][j] = (f32x4){0.f, 0.f, 0.f, 0.f};

    for (int ch = 0; ch < 6; ++ch) {
      int kc = ch * 32;
      __syncthreads();
      for (int i = t; i < 384; i += 256) {
        int k = i / 12, nq = (i % 12) * 4;
        float4 w = {0.f, 0.f, 0.f, 0.f};
        int kk = kc + k;
        if (kk < 180 && n0 + nq < 180)
          w = *(const float4*)&PW[(size_t)kk * 180 + n0 + nq];
        Bs[(nq + 0) * 40 + k] = (f16)w.x;
        Bs[(nq + 1) * 40 + k] = (f16)w.y;
        Bs[(nq + 2) * 40 + k] = (f16)w.z;
        Bs[(nq + 3) * 40 + k] = (f16)w.w;
      }
      __syncthreads();
      f16x8 af[2], bf[3];
#pragma unroll
      for (int mt = 0; mt < 2; ++mt) {
        int row = wave * 32 + mt * 16 + lm;
        af[mt] = *(const f16x8*)&Ax[row * 192 + kc + lq * 8];
      }
#pragma unroll
      for (int nt = 0; nt < 3; ++nt)
        bf[nt] = *(const f16x8*)&Bs[(nt * 16 + lm) * 40 + lq * 8];
#pragma unroll
      for (int mt = 0; mt < 2; ++mt)
#pragma unroll
        for (int nt = 0; nt < 3; ++nt)
          acc[mt][nt] = __builtin_amdgcn_mfma_f32_16x16x32_f16(
              af[mt], bf[nt], acc[mt][nt], 0, 0, 0);
    }

    float pb[3];
#pragma unroll
    for (int nt = 0; nt < 3; ++nt) {
      int col = n0 + nt * 16 + lm;
      pb[nt] = (col < 180) ? PB[col] : 0.f;
    }
    const float inv = 1.0f / 8192.0f;
#pragma unroll
    for (int mt = 0; mt < 2; ++mt) {
#pragma unroll
      for (int reg = 0; reg < 4; ++reg) {
        int w = w0r + wave * 32 + mt * 16 + lq * 4 + reg;
        int wi = w >> 8, l = w & 255;
        int b = wi >> 8, wy = (wi >> 4) & 15, wx = wi & 15;
        int ly = l >> 4, lx = l & 15;
        int p = (b << 16) | (((wy << 4) | ly) << 8) | ((wx << 4) | lx);
        float* orow = OUT + (size_t)p * 180;
#pragma unroll
        for (int nt = 0; nt < 3; ++nt) {
          int col = n0 + nt * 16 + lm;
          if (col < 180) orow[col] = acc[mt][nt][reg] * inv + pb[nt];
        }
      }
    }
  }
}

// ---------------------------------------------------------------------------
// Workspace layout (bytes) — peak requirement 66,060,288 (63.0 MB):
//  QX  f16 [512][256][180]  @ 0            (47,185,920)  qv*64 -> XS in place
//  T1  f16 [131072][36]     @ 47,185,920   ( 9,437,184)  dead after k2
//  T2  f16 [131072][36]     @ 56,623,104   ( 9,437,184)  dead after k3
//  PTAB f32 [961*6]         @ 47,185,920   over dead T1
//  RPB  f32 [6][256][64]    @ 47,212,544   over dead T1
//  CC   f32 [512][90][90]   @ 47,605,760   over dead T1/T2
// ---------------------------------------------------------------------------
extern "C" void kernel_launch(void* const* d_in, const int* in_sizes, int n_in,
                              void* d_out, int out_size, void* d_ws, size_t ws_size,
                              hipStream_t stream) {
  const float* X    = (const float*)d_in[0];
  const float* W1   = (const float*)d_in[1];
  const float* B1   = (const float*)d_in[2];
  const float* W2   = (const float*)d_in[3];
  const float* B2   = (const float*)d_in[4];
  const float* W3   = (const float*)d_in[5];
  const float* B3c  = (const float*)d_in[6];
  const float* WD   = (const float*)d_in[7];
  const float* BD   = (const float*)d_in[8];
  const float* SLW  = (const float*)d_in[9];
  const float* SLB  = (const float*)d_in[10];
  const float* PPW  = (const float*)d_in[11];
  const float* PPB  = (const float*)d_in[12];
  const float* LN1G = (const float*)d_in[13];
  const float* LN1B = (const float*)d_in[14];
  const float* M1W  = (const float*)d_in[15];
  const float* M1B  = (const float*)d_in[16];
  const float* LN2G = (const float*)d_in[17];
  const float* LN2B = (const float*)d_in[18];
  const float* M2W  = (const float*)d_in[19];
  const float* M2B  = (const float*)d_in[20];
  const float* LN3G = (const float*)d_in[21];
  const float* LN3B = (const float*)d_in[22];
  const float* M3W  = (const float*)d_in[23];
  const float* M3B  = (const float*)d_in[24];
  const float* PW   = (const float*)d_in[25];
  const float* PB   = (const float*)d_in[26];
  float* OUT = (float*)d_out;

  char* ws = (char*)d_ws;
  __half* QX  = (__half*)(ws);
  __half* T1  = (__half*)(ws + 47185920);
  __half* T2  = (__half*)(ws + 56623104);
  float* PTAB = (float*)(ws + 47185920);
  float* RPB  = (float*)(ws + 47212544);
  float* CC   = (float*)(ws + 47605760);

  hipLaunchKernelGGL(k1_conv1, dim3(1024), dim3(256), 0, stream, X, W1, B1, T1);
  hipLaunchKernelGGL(k2_conv2, dim3(2048), dim3(256), 0, stream, T1, W2, B2, T2);
  hipLaunchKernelGGL(k3_qv, dim3(1024), dim3(256), 0, stream, X, T2, W3, B3c, WD, BD, QX);
  hipLaunchKernelGGL(k5a_posmlp, dim3(4), dim3(256), 0, stream,
                     PPW, PPB, LN1G, LN1B, M1W, M1B, LN2G, LN2B, M2W, M2B,
                     LN3G, LN3B, M3W, M3B, PTAB);
  hipLaunchKernelGGL(k5b_rpb, dim3(384), dim3(256), 0, stream, PTAB, RPB);
  hipLaunchKernelGGL(k7a_cc, dim3(512), dim3(256), 0, stream, QX, CC);
  hipLaunchKernelGGL(kA_xsp, dim3(512), dim3(256), 0, stream, QX, RPB, SLW, SLB);
  hipLaunchKernelGGL(kB_xch, dim3(512), dim3(256), 0, stream, QX, CC);
  hipLaunchKernelGGL(k8_proj, dim3(1024), dim3(256), 0, stream, QX, PW, PB, OUT);
}

// Round 2
// 682.198 us; speedup vs baseline: 1.1759x; 1.1720x over previous
//
#include <hip/hip_runtime.h>
#include <hip/hip_fp16.h>

typedef unsigned int uint32;
typedef _Float16 f16;
typedef f16 f16x4 __attribute__((ext_vector_type(4)));
typedef f16 f16x8 __attribute__((ext_vector_type(8)));
typedef float f32x4 __attribute__((ext_vector_type(4)));

__device__ __forceinline__ float h2f(__half v) { return __half2float(v); }
__device__ __forceinline__ __half f2h(float v) { return __float2half(v); }

// ---------------------------------------------------------------------------
// K1: t1 = leaky_relu(x @ conv1_w + conv1_b)  (131072,180)->(131072,36) f16
// ---------------------------------------------------------------------------
__global__ __launch_bounds__(256) void k1_conv1(const float* __restrict__ X,
                                                const float* __restrict__ W1,
                                                const float* __restrict__ B1,
                                                __half* __restrict__ T1) {
  __shared__ float sm[60 * 132 + 60 * 36];
  float* Xt = sm;              // [60][132] (128 + pad4), k-major
  float* Ws = sm + 60 * 132;   // [60][36]
  int t = threadIdx.x;
  int p0 = blockIdx.x * 128;
  bool act = t < 144;
  int r0 = (t / 9) * 4, c0 = (t % 9) * 4;
  float acc[2][16];
#pragma unroll
  for (int h = 0; h < 2; ++h)
#pragma unroll
    for (int i = 0; i < 16; ++i) acc[h][i] = 0.f;

  for (int chunk = 0; chunk < 3; ++chunk) {
    __syncthreads();
    int kc = chunk * 60;
    for (int i = t; i < 128 * 60; i += 256) {
      int m = i / 60, k = i % 60;
      Xt[k * 132 + m] = X[(size_t)(p0 + m) * 180 + kc + k];
    }
    for (int i = t; i < 60 * 36; i += 256) {
      int k = i / 36, c = i % 36;
      Ws[k * 36 + c] = W1[(kc + k) * 36 + c];
    }
    __syncthreads();
    if (act) {
      for (int k = 0; k < 60; ++k) {
        float4 a0 = *(const float4*)&Xt[k * 132 + r0];
        float4 a1 = *(const float4*)&Xt[k * 132 + r0 + 64];
        float4 b  = *(const float4*)&Ws[k * 36 + c0];
        float av0[4] = {a0.x, a0.y, a0.z, a0.w};
        float av1[4] = {a1.x, a1.y, a1.z, a1.w};
        float bv[4]  = {b.x, b.y, b.z, b.w};
#pragma unroll
        for (int i = 0; i < 4; ++i)
#pragma unroll
          for (int j = 0; j < 4; ++j) {
            acc[0][i * 4 + j] += av0[i] * bv[j];
            acc[1][i * 4 + j] += av1[i] * bv[j];
          }
      }
    }
  }
  if (!act) return;
  float bb[4];
#pragma unroll
  for (int i = 0; i < 4; ++i) bb[i] = B1[c0 + i];
#pragma unroll
  for (int h = 0; h < 2; ++h)
#pragma unroll
    for (int ri = 0; ri < 4; ++ri) {
      int p = p0 + h * 64 + r0 + ri;
      __half* o = T1 + (size_t)p * 36 + c0;
      __half2 h01, h23;
      float v0 = acc[h][ri * 4 + 0] + bb[0];
      float v1 = acc[h][ri * 4 + 1] + bb[1];
      float v2 = acc[h][ri * 4 + 2] + bb[2];
      float v3 = acc[h][ri * 4 + 3] + bb[3];
      h01.x = f2h(v0 > 0.f ? v0 : 0.2f * v0);
      h01.y = f2h(v1 > 0.f ? v1 : 0.2f * v1);
      h23.x = f2h(v2 > 0.f ? v2 : 0.2f * v2);
      h23.y = f2h(v3 > 0.f ? v3 : 0.2f * v3);
      *(__half2*)o = h01;
      *(__half2*)(o + 2) = h23;
    }
}

// ---------------------------------------------------------------------------
// K2: t2 = leaky_relu(conv3x3(t1) + conv2_b), SAME. 64 px x 36 co tile.
// ---------------------------------------------------------------------------
__global__ __launch_bounds__(256) void k2_conv2(const __half* __restrict__ T1,
                                                const float* __restrict__ W2,
                                                const float* __restrict__ B2,
                                                __half* __restrict__ T2) {
  __shared__ float ins[3 * 68 * 37];   // [kh][xx][ci], stride 37
  __shared__ float ws2[9 * 36 * 36];   // [kh*3+kw][ci][co]
  int t = threadIdx.x;
  int p0 = blockIdx.x * 64;
  int b = p0 >> 16, y = (p0 >> 8) & 255, x0 = p0 & 255;
  for (int i = t; i < 11664; i += 256) ws2[i] = W2[i];
  for (int i = t; i < 3 * 66 * 36; i += 256) {
    int kh = i / 2376, rem = i % 2376;
    int xx = rem / 36, ci = rem % 36;
    int ry = y + kh - 1, gx = x0 + xx - 1;
    float v = 0.f;
    if ((unsigned)ry < 256u && (unsigned)gx < 256u)
      v = h2f(T1[((size_t)(b * 256 + ry) * 256 + gx) * 36 + ci]);
    ins[kh * 2516 + xx * 37 + ci] = v;
  }
  __syncthreads();
  bool act = t < 144;
  if (!act) return;
  int pl = (t / 9) * 4, c0 = (t % 9) * 4;
  float acc[16];
#pragma unroll
  for (int i = 0; i < 16; ++i) acc[i] = 0.f;
  for (int kh = 0; kh < 3; ++kh) {
    const float* base = ins + kh * 2516;
    for (int ci = 0; ci < 36; ++ci) {
      float rv[6];
#pragma unroll
      for (int u = 0; u < 6; ++u) rv[u] = base[(pl + u) * 37 + ci];
#pragma unroll
      for (int kw = 0; kw < 3; ++kw) {
        float4 w = *(const float4*)&ws2[((kh * 3 + kw) * 36 + ci) * 36 + c0];
        float wv[4] = {w.x, w.y, w.z, w.w};
#pragma unroll
        for (int jj = 0; jj < 4; ++jj)
#pragma unroll
          for (int i2 = 0; i2 < 4; ++i2)
            acc[jj * 4 + i2] += rv[jj + kw] * wv[i2];
      }
    }
  }
  float bb[4];
#pragma unroll
  for (int i = 0; i < 4; ++i) bb[i] = B2[c0 + i];
#pragma unroll
  for (int jj = 0; jj < 4; ++jj) {
    int p = p0 + pl + jj;
    __half* o = T2 + (size_t)p * 36 + c0;
    float v0 = acc[jj * 4 + 0] + bb[0];
    float v1 = acc[jj * 4 + 1] + bb[1];
    float v2 = acc[jj * 4 + 2] + bb[2];
    float v3 = acc[jj * 4 + 3] + bb[3];
    __half2 h01, h23;
    h01.x = f2h(v0 > 0.f ? v0 : 0.2f * v0);
    h01.y = f2h(v1 > 0.f ? v1 : 0.2f * v1);
    h23.x = f2h(v2 > 0.f ? v2 : 0.2f * v2);
    h23.y = f2h(v3 > 0.f ? v3 : 0.2f * v3);
    *(__half2*)o = h01;
    *(__half2*)(o + 2) = h23;
  }
}

// ---------------------------------------------------------------------------
// K3 (MFMA): qv = (t2 @ conv3_w + b3) * (x @ dfe_lin_w + bd), stored x64 f16
// windowed. Persistent-A: each block owns 128 rows, computes all 180 cols.
// ---------------------------------------------------------------------------
__global__ __launch_bounds__(256) void k3_qv(const float* __restrict__ X,
                                             const __half* __restrict__ T2,
                                             const float* __restrict__ W3,
                                             const float* __restrict__ B3,
                                             const float* __restrict__ WD,
                                             const float* __restrict__ BD,
                                             __half* __restrict__ QX) {
  __shared__ f16 Ax[128 * 192];  // X tile, K=180 zero-padded to 192
  __shared__ f16 At[128 * 40];   // T2 tile, K=36 zero-padded to 40
  __shared__ f16 Bs[48 * 40];    // weight chunk, n-major
  int t = threadIdx.x;
  int p0 = blockIdx.x * 128;
  int lane = t & 63, wave = t >> 6;
  int lm = lane & 15, lq = lane >> 4;

  // ---- stage T2 tile once (uint2 = 4 f16) ----
  for (int i = t; i < 1280; i += 256) {
    int m = i / 10, kq = (i % 10) * 4;
    uint2 val = {0u, 0u};
    if (kq < 36) val = *(const uint2*)&T2[(size_t)(p0 + m) * 36 + kq];
    *(uint2*)&At[m * 40 + kq] = val;
  }
  // ---- stage X tile once, f32 -> f16 ----
  for (int i = t; i < 6144; i += 256) {
    int m = i / 48, kq = (i % 48) * 4;
    union { f16 h[4]; uint2 u; } val;
    val.u.x = 0u; val.u.y = 0u;
    if (kq < 180) {
      float4 x = *(const float4*)&X[(size_t)(p0 + m) * 180 + kq];
      val.h[0] = (f16)x.x; val.h[1] = (f16)x.y;
      val.h[2] = (f16)x.z; val.h[3] = (f16)x.w;
    }
    *(uint2*)&Ax[m * 192 + kq] = val.u;
  }

  for (int bn = 0; bn < 4; ++bn) {
    int n0 = bn * 48;
    f32x4 accC[2][3], accD[2][3];
#pragma unroll
    for (int i = 0; i < 2; ++i)
#pragma unroll
      for (int j = 0; j < 3; ++j) {
        accC[i][j] = (f32x4){0.f, 0.f, 0.f, 0.f};
        accD[i][j] = (f32x4){0.f, 0.f, 0.f, 0.f};
      }

    // ---- phase 1: accC = T2 @ W3 (K=36, chunks of 32) ----
    for (int ch = 0; ch < 2; ++ch) {
      int kc = ch * 32;
      __syncthreads();
      for (int i = t; i < 384; i += 256) {
        int k = i / 12, nq = (i % 12) * 4;
        float4 w = {0.f, 0.f, 0.f, 0.f};
        int kk = kc + k;
        if (kk < 36 && n0 + nq < 180)
          w = *(const float4*)&W3[(size_t)kk * 180 + n0 + nq];
        Bs[(nq + 0) * 40 + k] = (f16)w.x;
        Bs[(nq + 1) * 40 + k] = (f16)w.y;
        Bs[(nq + 2) * 40 + k] = (f16)w.z;
        Bs[(nq + 3) * 40 + k] = (f16)w.w;
      }
      __syncthreads();
      f16x8 af[2], bf[3];
#pragma unroll
      for (int mt = 0; mt < 2; ++mt) {
        int row = wave * 32 + mt * 16 + lm;
        if (ch == 0) {
          af[mt] = *(const f16x8*)&At[row * 40 + lq * 8];
        } else {
          f16x8 z = {(f16)0, (f16)0, (f16)0, (f16)0, (f16)0, (f16)0, (f16)0, (f16)0};
          af[mt] = (lq == 0) ? *(const f16x8*)&At[row * 40 + 32] : z;
        }
      }
#pragma unroll
      for (int nt = 0; nt < 3; ++nt)
        bf[nt] = *(const f16x8*)&Bs[(nt * 16 + lm) * 40 + lq * 8];
#pragma unroll
      for (int mt = 0; mt < 2; ++mt)
#pragma unroll
        for (int nt = 0; nt < 3; ++nt)
          accC[mt][nt] = __builtin_amdgcn_mfma_f32_16x16x32_f16(
              af[mt], bf[nt], accC[mt][nt], 0, 0, 0);
    }

    // ---- phase 2: accD = X @ WD (K=180, 6 chunks of 32) ----
    for (int ch = 0; ch < 6; ++ch) {
      int kc = ch * 32;
      __syncthreads();
      for (int i = t; i < 384; i += 256) {
        int k = i / 12, nq = (i % 12) * 4;
        float4 w = {0.f, 0.f, 0.f, 0.f};
        int kk = kc + k;
        if (kk < 180 && n0 + nq < 180)
          w = *(const float4*)&WD[(size_t)kk * 180 + n0 + nq];
        Bs[(nq + 0) * 40 + k] = (f16)w.x;
        Bs[(nq + 1) * 40 + k] = (f16)w.y;
        Bs[(nq + 2) * 40 + k] = (f16)w.z;
        Bs[(nq + 3) * 40 + k] = (f16)w.w;
      }
      __syncthreads();
      f16x8 af[2], bf[3];
#pragma unroll
      for (int mt = 0; mt < 2; ++mt) {
        int row = wave * 32 + mt * 16 + lm;
        af[mt] = *(const f16x8*)&Ax[row * 192 + kc + lq * 8];
      }
#pragma unroll
      for (int nt = 0; nt < 3; ++nt)
        bf[nt] = *(const f16x8*)&Bs[(nt * 16 + lm) * 40 + lq * 8];
#pragma unroll
      for (int mt = 0; mt < 2; ++mt)
#pragma unroll
        for (int nt = 0; nt < 3; ++nt)
          accD[mt][nt] = __builtin_amdgcn_mfma_f32_16x16x32_f16(
              af[mt], bf[nt], accD[mt][nt], 0, 0, 0);
    }

    // ---- epilogue ----
    float cb[3], db[3];
#pragma unroll
    for (int nt = 0; nt < 3; ++nt) {
      int col = n0 + nt * 16 + lm;
      cb[nt] = (col < 180) ? B3[col] : 0.f;
      db[nt] = (col < 180) ? BD[col] : 0.f;
    }
#pragma unroll
    for (int mt = 0; mt < 2; ++mt) {
#pragma unroll
      for (int reg = 0; reg < 4; ++reg) {
        int p = p0 + wave * 32 + mt * 16 + lq * 4 + reg;
        int b = p >> 16, y = (p >> 8) & 255, x = p & 255;
        int wi = (b << 8) | ((y >> 4) << 4) | (x >> 4);
        int l = ((y & 15) << 4) | (x & 15);
        __half* orow = QX + ((size_t)(wi * 256 + l)) * 180;
#pragma unroll
        for (int nt = 0; nt < 3; ++nt) {
          int col = n0 + nt * 16 + lm;
          if (col < 180)
            orow[col] = f2h((accC[mt][nt][reg] + cb[nt]) *
                            (accD[mt][nt][reg] + db[nt]) * 64.f);
        }
      }
    }
  }
}

// ---------------------------------------------------------------------------
// K5a: position-bias MLP over 961 grid points -> PTAB[961][6] f32
// ---------------------------------------------------------------------------
__device__ __forceinline__ void ln_relu11(const float* p, const float* g,
                                          const float* b, float* r) {
  float m = 0.f;
#pragma unroll
  for (int j = 0; j < 11; ++j) m += p[j];
  m *= (1.0f / 11.0f);
  float v = 0.f;
#pragma unroll
  for (int j = 0; j < 11; ++j) { float d = p[j] - m; v += d * d; }
  v *= (1.0f / 11.0f);
  float inv = 1.0f / sqrtf(v + 1e-5f);
#pragma unroll
  for (int j = 0; j < 11; ++j) {
    float xn = (p[j] - m) * inv * g[j] + b[j];
    r[j] = fmaxf(xn, 0.f);
  }
}
__device__ __forceinline__ void mm11(const float* r, const float* W,
                                     const float* b, float* o) {
#pragma unroll
  for (int j2 = 0; j2 < 11; ++j2) {
    float s = b[j2];
#pragma unroll
    for (int j = 0; j < 11; ++j) s += r[j] * W[j * 11 + j2];
    o[j2] = s;
  }
}

__global__ __launch_bounds__(256) void k5a_posmlp(
    const float* PPW, const float* PPB,
    const float* LN1G, const float* LN1B, const float* M1W, const float* M1B,
    const float* LN2G, const float* LN2B, const float* M2W, const float* M2B,
    const float* LN3G, const float* LN3B, const float* M3W, const float* M3B,
    float* __restrict__ PTAB) {
  int t = blockIdx.x * 256 + threadIdx.x;
  if (t >= 961) return;
  float g0 = (float)(t / 31) - 15.0f;
  float g1 = (float)(t % 31) - 15.0f;
  float p[11], r[11];
#pragma unroll
  for (int j = 0; j < 11; ++j)
    p[j] = g0 * PPW[j] + g1 * PPW[11 + j] + PPB[j];
  ln_relu11(p, LN1G, LN1B, r);
  mm11(r, M1W, M1B, p);
  ln_relu11(p, LN2G, LN2B, r);
  mm11(r, M2W, M2B, p);
  ln_relu11(p, LN3G, LN3B, r);
#pragma unroll
  for (int h = 0; h < 6; ++h) {
    float s = M3B[h];
#pragma unroll
    for (int j = 0; j < 11; ++j) s += r[j] * M3W[j * 6 + h];
    PTAB[t * 6 + h] = s;
  }
}

// ---------------------------------------------------------------------------
// K5b: RPB[h][l][m] = mean over 2x2 of PTAB[(dr+15)*31+(dc+15)][h]
// ---------------------------------------------------------------------------
__global__ __launch_bounds__(256) void k5b_rpb(const float* __restrict__ PTAB,
                                               float* __restrict__ RPB) {
  int t = blockIdx.x * 256 + threadIdx.x;  // < 98304
  int m = t & 63;
  int l = (t >> 6) & 255;
  int h = t >> 14;
  int mh = m >> 3, mw = m & 7;
  int qr = l >> 4, qc = l & 15;
  float s = 0.f;
#pragma unroll
  for (int rh = 0; rh < 2; ++rh)
#pragma unroll
    for (int rw = 0; rw < 2; ++rw) {
      int dr = qr - (mh * 2 + rh) + 15;
      int dc = qc - (mw * 2 + rw) + 15;
      s += PTAB[(dr * 31 + dc) * 6 + h];
    }
  RPB[t] = 0.25f * s;
}

// ---------------------------------------------------------------------------
// K7a: cc[wi][c][d] = sum_l q[l][c]*v[l][d] / 256, f32 out (true scale).
// ---------------------------------------------------------------------------
__global__ __launch_bounds__(256) void k7a_cc(const __half* __restrict__ QX,
                                              float* __restrict__ CC) {
  __shared__ __half qs[64 * 90];
  __shared__ __half vs[64 * 90];
  int wi = blockIdx.x, t = threadIdx.x;
  int c0 = (t % 15) * 6, d0 = (t / 15) * 6;
  bool act = t < 225;
  float acc[36];
#pragma unroll
  for (int i = 0; i < 36; ++i) acc[i] = 0.f;
  const uint32* G = (const uint32*)(QX + (size_t)wi * 46080);
  uint32* qsw = (uint32*)qs;
  uint32* vsw = (uint32*)vs;
  for (int pass = 0; pass < 4; ++pass) {
    __syncthreads();
    for (int i = t; i < 2880; i += 256) {
      int l = i / 45, k = i % 45;
      int gw = (pass * 64 + l) * 90;
      qsw[l * 45 + k] = G[gw + k];
      vsw[l * 45 + k] = G[gw + 45 + k];
    }
    __syncthreads();
    if (act) {
      for (int l = 0; l < 64; ++l) {
        const __half2* qh = (const __half2*)&qs[l * 90 + c0];
        const __half2* vh = (const __half2*)&vs[l * 90 + d0];
        float a[6], b[6];
#pragma unroll
        for (int k = 0; k < 3; ++k) {
          __half2 x = qh[k];
          a[2 * k] = __low2float(x); a[2 * k + 1] = __high2float(x);
          __half2 y = vh[k];
          b[2 * k] = __low2float(y); b[2 * k + 1] = __high2float(y);
        }
#pragma unroll
        for (int i = 0; i < 6; ++i)
#pragma unroll
          for (int j = 0; j < 6; ++j) acc[i * 6 + j] += a[i] * b[j];
      }
    }
  }
  if (act) {
    const float s = 1.0f / (256.0f * 4096.0f);
#pragma unroll
    for (int i = 0; i < 6; ++i)
#pragma unroll
      for (int j = 0; j < 6; ++j)
        CC[((size_t)(wi * 90 + c0 + i)) * 90 + d0 + j] = acc[i * 6 + j] * s;
  }
}

// ---------------------------------------------------------------------------
// KA (MFMA): per window, per head h:
//   corr^T(64x256) = vp(64x16) x q^T      [mfma_f32_16x16x16f16]
//   corr' = (corr^T * 1/960 + 256*rpb) -> f16 (B-frag layout = C layout!)
//   x_sp^T(16x256) = vpT(16x64) x corr'   [chained over 4 k-tiles]
// x_sp written in place over q-channels as 8192*x_sp (f16).
// LDS phases: U = v rows [256][90] -> build vpS[64][104] (m-major) and
// vpT[96][72] (c-major), c=15 slots ZERO; then U reused as qP [256][104]
// (16 c-slots per head, slot 15 zero). 80,384 B total -> 2 blocks/CU.
// ---------------------------------------------------------------------------
__global__ __launch_bounds__(256) void kA_xsp(__half* __restrict__ QX,
                                              const float* __restrict__ RPB,
                                              const float* __restrict__ SLW,
                                              const float* __restrict__ SLB) {
  __shared__ __align__(16) unsigned char SM[80384];
  f16* U   = (f16*)SM;                    // A: v [256][90]; B: qP [256][104]
  f16* vpS = (f16*)(SM + 53248);          // [64][104] m-major (A1 frags)
  f16* vpT = (f16*)(SM + 66560);          // [96][72]  c-major (A2 frags)
  int wi = blockIdx.x, t = threadIdx.x;
  __half* QW = QX + (size_t)wi * 46080;
  const uint32* G = (const uint32*)QW;
  uint32* Uw = (uint32*)U;

  // ---- phase A: stage v rows [256][90] (coalesced u32) ----
  for (int i = t; i < 11520; i += 256) {
    int l = i / 45, k = i % 45;
    Uw[l * 45 + k] = G[l * 90 + 45 + k];
  }
  __syncthreads();
  // ---- build vp in both layouts, x256 scale, c=15 slots = 0 ----
  float w0 = SLW[0], w1 = SLW[1], w2 = SLW[2], w3 = SLW[3];
  float sb = SLB[0];
  for (int e = t; e < 6144; e += 256) {
    int m = e & 63, idx = e >> 6;          // idx = h*16 + c
    int c = idx & 15, h = idx >> 4;
    f16 val = (f16)0;
    if (c < 15) {
      int ch = h * 15 + c;
      int lb = (m >> 3) * 32 + (m & 7) * 2;
      float s = w0 * (float)U[lb * 90 + ch] + w1 * (float)U[(lb + 1) * 90 + ch]
              + w2 * (float)U[(lb + 16) * 90 + ch] + w3 * (float)U[(lb + 17) * 90 + ch];
      val = (f16)(s * 4.f + sb * 256.f);
    }
    vpS[m * 104 + idx] = val;
    vpT[idx * 72 + m] = val;
  }
  __syncthreads();
  // ---- phase B: overwrite U with qP [256][104], 16 c-slots/head ----
  for (int j = t; j < 1536; j += 256) {
    int h = j >> 8, l = j & 255;
    U[l * 104 + h * 16 + 15] = (f16)0;
  }
  for (int i = t; i < 11520; i += 256) {
    int l = i / 45, k = i % 45;
    union { uint32 w; f16 h[2]; } cv;
    cv.w = G[l * 90 + k];
    int cg0 = 2 * k, cg1 = 2 * k + 1;
    int h0 = cg0 / 15, c0 = cg0 - h0 * 15;
    int h1 = cg1 / 15, c1 = cg1 - h1 * 15;
    U[l * 104 + h0 * 16 + c0] = cv.h[0];
    U[l * 104 + h1 * 16 + c1] = cv.h[1];
  }
  __syncthreads();

  int lane = t & 63, w = t >> 6;
  int lm = lane & 15, lq = lane >> 4;
  const float invA = 1.0f / 960.0f;        // 256 / (15*16384)
  for (int h = 0; h < 6; ++h) {
    f16x4 a1[4], b1[4];
#pragma unroll
    for (int mt = 0; mt < 4; ++mt)
      a1[mt] = *(const f16x4*)&vpS[(mt * 16 + lm) * 104 + h * 16 + lq * 4];
#pragma unroll
    for (int lt = 0; lt < 4; ++lt)
      b1[lt] = *(const f16x4*)&U[(w * 64 + lt * 16 + lm) * 104 + h * 16 + lq * 4];
    f32x4 acc1[4][4];
#pragma unroll
    for (int mt = 0; mt < 4; ++mt)
#pragma unroll
      for (int lt = 0; lt < 4; ++lt)
        acc1[mt][lt] = __builtin_amdgcn_mfma_f32_16x16x16f16(
            a1[mt], b1[lt], (f32x4){0.f, 0.f, 0.f, 0.f}, 0, 0, 0);
    // corr' = acc1/960 + 256*rpb  -> f16; C layout == B2 frag layout
    f16x4 b2[4][4];
#pragma unroll
    for (int lt = 0; lt < 4; ++lt) {
      int l = w * 64 + lt * 16 + lm;
      const float* rp = RPB + ((size_t)(h * 256 + l)) * 64;
#pragma unroll
      for (int mt = 0; mt < 4; ++mt) {
        float4 rv = *(const float4*)&rp[mt * 16 + lq * 4];
        f16x4 bb;
        bb[0] = (f16)(acc1[mt][lt][0] * invA + rv.x * 256.f);
        bb[1] = (f16)(acc1[mt][lt][1] * invA + rv.y * 256.f);
        bb[2] = (f16)(acc1[mt][lt][2] * invA + rv.z * 256.f);
        bb[3] = (f16)(acc1[mt][lt][3] * invA + rv.w * 256.f);
        b2[mt][lt] = bb;
      }
    }
    f16x4 a2[4];
#pragma unroll
    for (int kt = 0; kt < 4; ++kt)
      a2[kt] = *(const f16x4*)&vpT[(h * 16 + lm) * 72 + kt * 16 + lq * 4];
#pragma unroll
    for (int lt = 0; lt < 4; ++lt) {
      f32x4 acc2 = (f32x4){0.f, 0.f, 0.f, 0.f};
#pragma unroll
      for (int kt = 0; kt < 4; ++kt)
        acc2 = __builtin_amdgcn_mfma_f32_16x16x16f16(a2[kt], b2[kt][lt], acc2, 0, 0, 0);
      int l = w * 64 + lt * 16 + lm;
      __half* orow = QW + l * 180 + h * 15;
#pragma unroll
      for (int reg = 0; reg < 4; ++reg) {
        int c = lq * 4 + reg;
        if (c < 15) orow[c] = f2h(acc2[reg] * 0.125f);   // 65536*x_sp / 8
      }
    }
  }
}

// ---------------------------------------------------------------------------
// KB (MFMA): x_ch[l][c] = sum_d cc[c][d]*v[l][d], in place over v-channels
// as 8192*x_ch (f16). A = v [256][104] (d pad 90..95 = 0), B = cc [96][104]
// n-major f16 x65536 (all pads 0). 16x16x32 MFMA, 3 K-chunks, 4x6 tiles/wave.
// ---------------------------------------------------------------------------
__global__ __launch_bounds__(256) void kB_xch(__half* __restrict__ QX,
                                              const float* __restrict__ CC) {
  __shared__ __align__(16) f16 vA[256 * 104];
  __shared__ __align__(16) f16 ccB[96 * 104];
  int wi = blockIdx.x, t = threadIdx.x;
  __half* QW = QX + (size_t)wi * 46080;
  const uint32* G = (const uint32*)QW;
  uint32* vAw = (uint32*)vA;
  for (int i = t; i < 12288; i += 256) {   // 256 rows x 48 u32 (cols 0..95)
    int l = i / 48, kk = i % 48;
    vAw[l * 52 + kk] = (kk < 45) ? G[l * 90 + 45 + kk] : 0u;
  }
  const float* ccg = CC + (size_t)wi * 8100;
  uint32* ccw = (uint32*)ccB;
  for (int i = t; i < 4992; i += 256) {    // 96 rows x 52 u32, zero pads
    int c = i / 52, dd = i % 52;
    uint32 out = 0u;
    if (c < 90 && dd < 45) {
      float2 f = *(const float2*)&ccg[c * 90 + dd * 2];
      union { uint32 w; f16 h[2]; } cv;
      cv.h[0] = (f16)(f.x * 65536.f);
      cv.h[1] = (f16)(f.y * 65536.f);
      out = cv.w;
    }
    ccw[c * 52 + dd] = out;
  }
  __syncthreads();
  int lane = t & 63, w = t >> 6;
  int lm = lane & 15, lq = lane >> 4;
  f32x4 acc[4][6];
#pragma unroll
  for (int mt = 0; mt < 4; ++mt)
#pragma unroll
    for (int nt = 0; nt < 6; ++nt) acc[mt][nt] = (f32x4){0.f, 0.f, 0.f, 0.f};
  for (int kc = 0; kc < 3; ++kc) {
    f16x8 af[4], bf[6];
#pragma unroll
    for (int mt = 0; mt < 4; ++mt)
      af[mt] = *(const f16x8*)&vA[(w * 64 + mt * 16 + lm) * 104 + kc * 32 + lq * 8];
#pragma unroll
    for (int nt = 0; nt < 6; ++nt)
      bf[nt] = *(const f16x8*)&ccB[(nt * 16 + lm) * 104 + kc * 32 + lq * 8];
#pragma unroll
    for (int mt = 0; mt < 4; ++mt)
#pragma unroll
      for (int nt = 0; nt < 6; ++nt)
        acc[mt][nt] = __builtin_amdgcn_mfma_f32_16x16x32_f16(
            af[mt], bf[nt], acc[mt][nt], 0, 0, 0);
  }
  // D: col = lane&15 = c within nt, row = lq*4+reg = l within mt
#pragma unroll
  for (int mt = 0; mt < 4; ++mt) {
#pragma unroll
    for (int reg = 0; reg < 4; ++reg) {
      int l = w * 64 + mt * 16 + lq * 4 + reg;
      __half* orow = QW + l * 180 + 90;
#pragma unroll
      for (int nt = 0; nt < 6; ++nt) {
        int c = nt * 16 + lm;
        if (c < 90) orow[c] = f2h(acc[mt][nt][reg] * 0.001953125f);  // 2^22 -> 2^13
      }
    }
  }
}

// ---------------------------------------------------------------------------
// K8 (MFMA): out = (XS/8192) @ proj_w + proj_b, f32 out, window-reverse
// scatter. Persistent-A: XS tile staged once, loop bn over 48-col chunks.
// ---------------------------------------------------------------------------
__global__ __launch_bounds__(256) void k8_proj(const __half* __restrict__ XS,
                                               const float* __restrict__ PW,
                                               const float* __restrict__ PB,
                                               float* __restrict__ OUT) {
  __shared__ f16 Ax[128 * 192];
  __shared__ f16 Bs[48 * 40];
  int t = threadIdx.x;
  int w0r = blockIdx.x * 128;
  int lane = t & 63, wave = t >> 6;
  int lm = lane & 15, lq = lane >> 4;

  for (int i = t; i < 6144; i += 256) {
    int m = i / 48, kq = (i % 48) * 4;
    uint2 val = {0u, 0u};
    if (kq < 180) val = *(const uint2*)&XS[(size_t)(w0r + m) * 180 + kq];
    *(uint2*)&Ax[m * 192 + kq] = val;
  }

  for (int bn = 0; bn < 4; ++bn) {
    int n0 = bn * 48;
    f32x4 acc[2][3];
#pragma unroll
    for (int i = 0; i < 2; ++i)
#pragma unroll
      for (int j = 0; j < 3; ++j) acc[i][j] = (f32x4){0.f, 0.f, 0.f, 0.f};

    for (int ch = 0; ch < 6; ++ch) {
      int kc = ch * 32;
      __syncthreads();
      for (int i = t; i < 384; i += 256) {
        int k = i / 12, nq = (i % 12) * 4;
        float4 w = {0.f, 0.f, 0.f, 0.f};
        int kk = kc + k;
        if (kk < 180 && n0 + nq < 180)
          w = *(const float4*)&PW[(size_t)kk * 180 + n0 + nq];
        Bs[(nq + 0) * 40 + k] = (f16)w.x;
        Bs[(nq + 1) * 40 + k] = (f16)w.y;
        Bs[(nq + 2) * 40 + k] = (f16)w.z;
        Bs[(nq + 3) * 40 + k] = (f16)w.w;
      }
      __syncthreads();
      f16x8 af[2], bf[3];
#pragma unroll
      for (int mt = 0; mt < 2; ++mt) {
        int row = wave * 32 + mt * 16 + lm;
        af[mt] = *(const f16x8*)&Ax[row * 192 + kc + lq * 8];
      }
#pragma unroll
      for (int nt = 0; nt < 3; ++nt)
        bf[nt] = *(const f16x8*)&Bs[(nt * 16 + lm) * 40 + lq * 8];
#pragma unroll
      for (int mt = 0; mt < 2; ++mt)
#pragma unroll
        for (int nt = 0; nt < 3; ++nt)
          acc[mt][nt] = __builtin_amdgcn_mfma_f32_16x16x32_f16(
              af[mt], bf[nt], acc[mt][nt], 0, 0, 0);
    }

    float pb[3];
#pragma unroll
    for (int nt = 0; nt < 3; ++nt) {
      int col = n0 + nt * 16 + lm;
      pb[nt] = (col < 180) ? PB[col] : 0.f;
    }
    const float inv = 1.0f / 8192.0f;
#pragma unroll
    for (int mt = 0; mt < 2; ++mt) {
#pragma unroll
      for (int reg = 0; reg < 4; ++reg) {
        int w = w0r + wave * 32 + mt * 16 + lq * 4 + reg;
        int wi = w >> 8, l = w & 255;
        int b = wi >> 8, wy = (wi >> 4) & 15, wx = wi & 15;
        int ly = l >> 4, lx = l & 15;
        int p = (b << 16) | (((wy << 4) | ly) << 8) | ((wx << 4) | lx);
        float* orow = OUT + (size_t)p * 180;
#pragma unroll
        for (int nt = 0; nt < 3; ++nt) {
          int col = n0 + nt * 16 + lm;
          if (col < 180) orow[col] = acc[mt][nt][reg] * inv + pb[nt];
        }
      }
    }
  }
}

// ---------------------------------------------------------------------------
// Workspace layout (bytes) — peak requirement 66,060,288 (63.0 MB):
//  QX  f16 [512][256][180]  @ 0            (47,185,920)  qv*64 -> XS in place
//  T1  f16 [131072][36]     @ 47,185,920   ( 9,437,184)  dead after k2
//  T2  f16 [131072][36]     @ 56,623,104   ( 9,437,184)  dead after k3
//  PTAB f32 [961*6]         @ 47,185,920   over dead T1
//  RPB  f32 [6][256][64]    @ 47,212,544   over dead T1
//  CC   f32 [512][90][90]   @ 47,605,760   over dead T1/T2
// ---------------------------------------------------------------------------
extern "C" void kernel_launch(void* const* d_in, const int* in_sizes, int n_in,
                              void* d_out, int out_size, void* d_ws, size_t ws_size,
                              hipStream_t stream) {
  const float* X    = (const float*)d_in[0];
  const float* W1   = (const float*)d_in[1];
  const float* B1   = (const float*)d_in[2];
  const float* W2   = (const float*)d_in[3];
  const float* B2   = (const float*)d_in[4];
  const float* W3   = (const float*)d_in[5];
  const float* B3c  = (const float*)d_in[6];
  const float* WD   = (const float*)d_in[7];
  const float* BD   = (const float*)d_in[8];
  const float* SLW  = (const float*)d_in[9];
  const float* SLB  = (const float*)d_in[10];
  const float* PPW  = (const float*)d_in[11];
  const float* PPB  = (const float*)d_in[12];
  const float* LN1G = (const float*)d_in[13];
  const float* LN1B = (const float*)d_in[14];
  const float* M1W  = (const float*)d_in[15];
  const float* M1B  = (const float*)d_in[16];
  const float* LN2G = (const float*)d_in[17];
  const float* LN2B = (const float*)d_in[18];
  const float* M2W  = (const float*)d_in[19];
  const float* M2B  = (const float*)d_in[20];
  const float* LN3G = (const float*)d_in[21];
  const float* LN3B = (const float*)d_in[22];
  const float* M3W  = (const float*)d_in[23];
  const float* M3B  = (const float*)d_in[24];
  const float* PW   = (const float*)d_in[25];
  const float* PB   = (const float*)d_in[26];
  float* OUT = (float*)d_out;

  char* ws = (char*)d_ws;
  __half* QX  = (__half*)(ws);
  __half* T1  = (__half*)(ws + 47185920);
  __half* T2  = (__half*)(ws + 56623104);
  float* PTAB = (float*)(ws + 47185920);
  float* RPB  = (float*)(ws + 47212544);
  float* CC   = (float*)(ws + 47605760);

  hipLaunchKernelGGL(k1_conv1, dim3(1024), dim3(256), 0, stream, X, W1, B1, T1);
  hipLaunchKernelGGL(k2_conv2, dim3(2048), dim3(256), 0, stream, T1, W2, B2, T2);
  hipLaunchKernelGGL(k3_qv, dim3(1024), dim3(256), 0, stream, X, T2, W3, B3c, WD, BD, QX);
  hipLaunchKernelGGL(k5a_posmlp, dim3(4), dim3(256), 0, stream,
                     PPW, PPB, LN1G, LN1B, M1W, M1B, LN2G, LN2B, M2W, M2B,
                     LN3G, LN3B, M3W, M3B, PTAB);
  hipLaunchKernelGGL(k5b_rpb, dim3(384), dim3(256), 0, stream, PTAB, RPB);
  hipLaunchKernelGGL(k7a_cc, dim3(512), dim3(256), 0, stream, QX, CC);
  hipLaunchKernelGGL(kA_xsp, dim3(512), dim3(256), 0, stream, QX, RPB, SLW, SLB);
  hipLaunchKernelGGL(kB_xch, dim3(512), dim3(256), 0, stream, QX, CC);
  hipLaunchKernelGGL(k8_proj, dim3(1024), dim3(256), 0, stream, QX, PW, PB, OUT);
}

// Round 4
// 613.565 us; speedup vs baseline: 1.3074x; 1.1119x over previous
//
#include <hip/hip_runtime.h>
#include <hip/hip_fp16.h>

typedef unsigned int uint32;
typedef _Float16 f16;
typedef f16 f16x4 __attribute__((ext_vector_type(4)));
typedef f16 f16x8 __attribute__((ext_vector_type(8)));
typedef float f32x4 __attribute__((ext_vector_type(4)));

union U8 { f16x8 v; uint4 u4; uint2 u2[2]; f16 h[8]; };

__device__ __forceinline__ float h2f(__half v) { return __half2float(v); }
__device__ __forceinline__ __half f2h(float v) { return __float2half(v); }

// ---------------------------------------------------------------------------
// K1: t1 = leaky_relu(x @ conv1_w + conv1_b)  (131072,180)->(131072,36) f16
// ---------------------------------------------------------------------------
__global__ __launch_bounds__(256) void k1_conv1(const float* __restrict__ X,
                                                const float* __restrict__ W1,
                                                const float* __restrict__ B1,
                                                __half* __restrict__ T1) {
  __shared__ float sm[60 * 132 + 60 * 36];
  float* Xt = sm;              // [60][132] (128 + pad4), k-major
  float* Ws = sm + 60 * 132;   // [60][36]
  int t = threadIdx.x;
  int p0 = blockIdx.x * 128;
  bool act = t < 144;
  int r0 = (t / 9) * 4, c0 = (t % 9) * 4;
  float acc[2][16];
#pragma unroll
  for (int h = 0; h < 2; ++h)
#pragma unroll
    for (int i = 0; i < 16; ++i) acc[h][i] = 0.f;

  for (int chunk = 0; chunk < 3; ++chunk) {
    __syncthreads();
    int kc = chunk * 60;
    for (int i = t; i < 128 * 60; i += 256) {
      int m = i / 60, k = i % 60;
      Xt[k * 132 + m] = X[(size_t)(p0 + m) * 180 + kc + k];
    }
    for (int i = t; i < 60 * 36; i += 256) {
      int k = i / 36, c = i % 36;
      Ws[k * 36 + c] = W1[(kc + k) * 36 + c];
    }
    __syncthreads();
    if (act) {
      for (int k = 0; k < 60; ++k) {
        float4 a0 = *(const float4*)&Xt[k * 132 + r0];
        float4 a1 = *(const float4*)&Xt[k * 132 + r0 + 64];
        float4 b  = *(const float4*)&Ws[k * 36 + c0];
        float av0[4] = {a0.x, a0.y, a0.z, a0.w};
        float av1[4] = {a1.x, a1.y, a1.z, a1.w};
        float bv[4]  = {b.x, b.y, b.z, b.w};
#pragma unroll
        for (int i = 0; i < 4; ++i)
#pragma unroll
          for (int j = 0; j < 4; ++j) {
            acc[0][i * 4 + j] += av0[i] * bv[j];
            acc[1][i * 4 + j] += av1[i] * bv[j];
          }
      }
    }
  }
  if (!act) return;
  float bb[4];
#pragma unroll
  for (int i = 0; i < 4; ++i) bb[i] = B1[c0 + i];
#pragma unroll
  for (int h = 0; h < 2; ++h)
#pragma unroll
    for (int ri = 0; ri < 4; ++ri) {
      int p = p0 + h * 64 + r0 + ri;
      __half* o = T1 + (size_t)p * 36 + c0;
      __half2 h01, h23;
      float v0 = acc[h][ri * 4 + 0] + bb[0];
      float v1 = acc[h][ri * 4 + 1] + bb[1];
      float v2 = acc[h][ri * 4 + 2] + bb[2];
      float v3 = acc[h][ri * 4 + 3] + bb[3];
      h01.x = f2h(v0 > 0.f ? v0 : 0.2f * v0);
      h01.y = f2h(v1 > 0.f ? v1 : 0.2f * v1);
      h23.x = f2h(v2 > 0.f ? v2 : 0.2f * v2);
      h23.y = f2h(v3 > 0.f ? v3 : 0.2f * v3);
      *(__half2*)o = h01;
      *(__half2*)(o + 2) = h23;
    }
}

// ---------------------------------------------------------------------------
// K2: t2 = leaky_relu(conv3x3(t1) + conv2_b), SAME. 64 px x 36 co tile.
// ---------------------------------------------------------------------------
__global__ __launch_bounds__(256) void k2_conv2(const __half* __restrict__ T1,
                                                const float* __restrict__ W2,
                                                const float* __restrict__ B2,
                                                __half* __restrict__ T2) {
  __shared__ float ins[3 * 68 * 37];   // [kh][xx][ci], stride 37
  __shared__ float ws2[9 * 36 * 36];   // [kh*3+kw][ci][co]
  int t = threadIdx.x;
  int p0 = blockIdx.x * 64;
  int b = p0 >> 16, y = (p0 >> 8) & 255, x0 = p0 & 255;
  for (int i = t; i < 11664; i += 256) ws2[i] = W2[i];
  for (int i = t; i < 3 * 66 * 36; i += 256) {
    int kh = i / 2376, rem = i % 2376;
    int xx = rem / 36, ci = rem % 36;
    int ry = y + kh - 1, gx = x0 + xx - 1;
    float v = 0.f;
    if ((unsigned)ry < 256u && (unsigned)gx < 256u)
      v = h2f(T1[((size_t)(b * 256 + ry) * 256 + gx) * 36 + ci]);
    ins[kh * 2516 + xx * 37 + ci] = v;
  }
  __syncthreads();
  bool act = t < 144;
  if (!act) return;
  int pl = (t / 9) * 4, c0 = (t % 9) * 4;
  float acc[16];
#pragma unroll
  for (int i = 0; i < 16; ++i) acc[i] = 0.f;
  for (int kh = 0; kh < 3; ++kh) {
    const float* base = ins + kh * 2516;
    for (int ci = 0; ci < 36; ++ci) {
      float rv[6];
#pragma unroll
      for (int u = 0; u < 6; ++u) rv[u] = base[(pl + u) * 37 + ci];
#pragma unroll
      for (int kw = 0; kw < 3; ++kw) {
        float4 w = *(const float4*)&ws2[((kh * 3 + kw) * 36 + ci) * 36 + c0];
        float wv[4] = {w.x, w.y, w.z, w.w};
#pragma unroll
        for (int jj = 0; jj < 4; ++jj)
#pragma unroll
          for (int i2 = 0; i2 < 4; ++i2)
            acc[jj * 4 + i2] += rv[jj + kw] * wv[i2];
      }
    }
  }
  float bb[4];
#pragma unroll
  for (int i = 0; i < 4; ++i) bb[i] = B2[c0 + i];
#pragma unroll
  for (int jj = 0; jj < 4; ++jj) {
    int p = p0 + pl + jj;
    __half* o = T2 + (size_t)p * 36 + c0;
    float v0 = acc[jj * 4 + 0] + bb[0];
    float v1 = acc[jj * 4 + 1] + bb[1];
    float v2 = acc[jj * 4 + 2] + bb[2];
    float v3 = acc[jj * 4 + 3] + bb[3];
    __half2 h01, h23;
    h01.x = f2h(v0 > 0.f ? v0 : 0.2f * v0);
    h01.y = f2h(v1 > 0.f ? v1 : 0.2f * v1);
    h23.x = f2h(v2 > 0.f ? v2 : 0.2f * v2);
    h23.y = f2h(v3 > 0.f ? v3 : 0.2f * v3);
    *(__half2*)o = h01;
    *(__half2*)(o + 2) = h23;
  }
}

// ---------------------------------------------------------------------------
// K0_wt: transpose+convert W3/WD to n-major f16 tables with zero padding.
// WT3[192][40]: WT3[n][k] = W3[k][n] (n<180,k<36), else 0.
// WTD[192][192]: WTD[n][k] = WD[k][n] (n<180,k<180), else 0.
// ---------------------------------------------------------------------------
__global__ __launch_bounds__(256) void k0_wt(const float* __restrict__ SW3,
                                             const float* __restrict__ SWD,
                                             f16* __restrict__ WT3,
                                             f16* __restrict__ WTD) {
  int tid = blockIdx.x * 256 + threadIdx.x;
  int stride = gridDim.x * 256;
  for (int i = tid; i < 192 * 40; i += stride) {
    int n = i / 40, k = i % 40;
    WT3[i] = (n < 180 && k < 36) ? (f16)SW3[k * 180 + n] : (f16)0;
  }
  for (int i = tid; i < 192 * 192; i += stride) {
    int n = i / 192, k = i % 192;
    WTD[i] = (n < 180 && k < 180) ? (f16)SWD[k * 180 + n] : (f16)0;
  }
}

// K0_pw: same for proj_w -> PWT[192][192]. Launched AFTER k3 (lives over T2).
__global__ __launch_bounds__(256) void k0_pw(const float* __restrict__ SPW,
                                             f16* __restrict__ PWT) {
  int tid = blockIdx.x * 256 + threadIdx.x;
  int stride = gridDim.x * 256;
  for (int i = tid; i < 192 * 192; i += stride) {
    int n = i / 192, k = i % 192;
    PWT[i] = (n < 180 && k < 180) ? (f16)SPW[k * 180 + n] : (f16)0;
  }
}

// ---------------------------------------------------------------------------
// K3 (MFMA, no LDS, no barriers): qv = (t2@W3+b3)*(x@WD+bd), x64 f16,
// windowed scatter. A-fragments loaded straight from global into registers
// (held across all 4 bn); B-fragments are 16B loads from the L2-resident
// f16 transposed tables. Grid: 1024 blocks x 256 thr (4 waves, 32 rows/wave).
// ---------------------------------------------------------------------------
__global__ __launch_bounds__(256) void k3_qv(const float* __restrict__ X,
                                             const __half* __restrict__ T2,
                                             const f16* __restrict__ WT3,
                                             const f16* __restrict__ WTD,
                                             const float* __restrict__ B3,
                                             const float* __restrict__ BD,
                                             __half* __restrict__ QX) {
  int t = threadIdx.x;
  int p0 = blockIdx.x * 128;
  int lane = t & 63, wave = t >> 6;
  int lm = lane & 15, lq = lane >> 4;

  const f16x8 zero8 = {(f16)0,(f16)0,(f16)0,(f16)0,(f16)0,(f16)0,(f16)0,(f16)0};

  // ---- A-fragments in registers (reused across all bn) ----
  f16x8 ax[6][2];   // X rows, f32->f16, k = ch*32 + lq*8 (zeros for k>=180)
  f16x8 at0[2];     // T2 k-chunk 0 (k = lq*8, 0..31)
  f16x8 at1[2];     // T2 k-chunk 1 (lq==0: k=32..35 + zeros; else zero)
#pragma unroll
  for (int mt = 0; mt < 2; ++mt) {
    int row = p0 + wave * 32 + mt * 16 + lm;
    const float* xr = X + (size_t)row * 180;
#pragma unroll
    for (int ch = 0; ch < 6; ++ch) {
      int k0 = ch * 32 + lq * 8;
      U8 v; v.u4 = (uint4){0u, 0u, 0u, 0u};
      if (k0 + 8 <= 180) {
        float4 a = *(const float4*)&xr[k0];
        float4 b = *(const float4*)&xr[k0 + 4];
        v.h[0]=(f16)a.x; v.h[1]=(f16)a.y; v.h[2]=(f16)a.z; v.h[3]=(f16)a.w;
        v.h[4]=(f16)b.x; v.h[5]=(f16)b.y; v.h[6]=(f16)b.z; v.h[7]=(f16)b.w;
      } else if (k0 < 180) {  // k0 == 176
        float4 a = *(const float4*)&xr[k0];
        v.h[0]=(f16)a.x; v.h[1]=(f16)a.y; v.h[2]=(f16)a.z; v.h[3]=(f16)a.w;
      }
      ax[ch][mt] = v.v;
    }
    const f16* tr = (const f16*)T2 + (size_t)row * 36;
    U8 tv;
    tv.u2[0] = *(const uint2*)&tr[lq * 8];
    tv.u2[1] = *(const uint2*)&tr[lq * 8 + 4];
    at0[mt] = tv.v;
    U8 t1v; t1v.u4 = (uint4){0u, 0u, 0u, 0u};
    if (lq == 0) t1v.u2[0] = *(const uint2*)&tr[32];  // k=32..35, 8B (in-bounds)
    at1[mt] = t1v.v;
  }

  for (int bn = 0; bn < 4; ++bn) {
    int n0 = bn * 48;
    f32x4 accC[2][3], accD[2][3];
#pragma unroll
    for (int i = 0; i < 2; ++i)
#pragma unroll
      for (int j = 0; j < 3; ++j) {
        accC[i][j] = (f32x4){0.f, 0.f, 0.f, 0.f};
        accD[i][j] = (f32x4){0.f, 0.f, 0.f, 0.f};
      }

    // ---- phase 1: accC = T2 @ W3 (K=36 via 2 chunks) ----
#pragma unroll
    for (int nt = 0; nt < 3; ++nt) {
      int n = n0 + nt * 16 + lm;            // < 192, rows >=180 are zeros
      f16x8 b0 = *(const f16x8*)&WT3[n * 40 + lq * 8];
      f16x8 b1 = (lq == 0) ? *(const f16x8*)&WT3[n * 40 + 32] : zero8;
#pragma unroll
      for (int mt = 0; mt < 2; ++mt) {
        accC[mt][nt] = __builtin_amdgcn_mfma_f32_16x16x32_f16(
            at0[mt], b0, accC[mt][nt], 0, 0, 0);
        accC[mt][nt] = __builtin_amdgcn_mfma_f32_16x16x32_f16(
            at1[mt], b1, accC[mt][nt], 0, 0, 0);
      }
    }

    // ---- phase 2: accD = X @ WD (K=180 via 6 chunks) ----
#pragma unroll
    for (int ch = 0; ch < 6; ++ch) {
#pragma unroll
      for (int nt = 0; nt < 3; ++nt) {
        int n = n0 + nt * 16 + lm;
        f16x8 bf = *(const f16x8*)&WTD[n * 192 + ch * 32 + lq * 8];
        accD[0][nt] = __builtin_amdgcn_mfma_f32_16x16x32_f16(
            ax[ch][0], bf, accD[0][nt], 0, 0, 0);
        accD[1][nt] = __builtin_amdgcn_mfma_f32_16x16x32_f16(
            ax[ch][1], bf, accD[1][nt], 0, 0, 0);
      }
    }

    // ---- epilogue: qv = (accC+b3)*(accD+bd)*64, windowed f16 scatter ----
    float cb[3], db[3];
#pragma unroll
    for (int nt = 0; nt < 3; ++nt) {
      int col = n0 + nt * 16 + lm;
      cb[nt] = (col < 180) ? B3[col] : 0.f;
      db[nt] = (col < 180) ? BD[col] : 0.f;
    }
#pragma unroll
    for (int mt = 0; mt < 2; ++mt) {
#pragma unroll
      for (int reg = 0; reg < 4; ++reg) {
        int p = p0 + wave * 32 + mt * 16 + lq * 4 + reg;
        int b = p >> 16, y = (p >> 8) & 255, x = p & 255;
        int wi = (b << 8) | ((y >> 4) << 4) | (x >> 4);
        int l = ((y & 15) << 4) | (x & 15);
        __half* orow = QX + ((size_t)(wi * 256 + l)) * 180;
#pragma unroll
        for (int nt = 0; nt < 3; ++nt) {
          int col = n0 + nt * 16 + lm;
          if (col < 180)
            orow[col] = f2h((accC[mt][nt][reg] + cb[nt]) *
                            (accD[mt][nt][reg] + db[nt]) * 64.f);
        }
      }
    }
  }
}

// ---------------------------------------------------------------------------
// K5a: position-bias MLP over 961 grid points -> PTAB[961][6] f32
// ---------------------------------------------------------------------------
__device__ __forceinline__ void ln_relu11(const float* p, const float* g,
                                          const float* b, float* r) {
  float m = 0.f;
#pragma unroll
  for (int j = 0; j < 11; ++j) m += p[j];
  m *= (1.0f / 11.0f);
  float v = 0.f;
#pragma unroll
  for (int j = 0; j < 11; ++j) { float d = p[j] - m; v += d * d; }
  v *= (1.0f / 11.0f);
  float inv = 1.0f / sqrtf(v + 1e-5f);
#pragma unroll
  for (int j = 0; j < 11; ++j) {
    float xn = (p[j] - m) * inv * g[j] + b[j];
    r[j] = fmaxf(xn, 0.f);
  }
}
__device__ __forceinline__ void mm11(const float* r, const float* W,
                                     const float* b, float* o) {
#pragma unroll
  for (int j2 = 0; j2 < 11; ++j2) {
    float s = b[j2];
#pragma unroll
    for (int j = 0; j < 11; ++j) s += r[j] * W[j * 11 + j2];
    o[j2] = s;
  }
}

__global__ __launch_bounds__(256) void k5a_posmlp(
    const float* PPW, const float* PPB,
    const float* LN1G, const float* LN1B, const float* M1W, const float* M1B,
    const float* LN2G, const float* LN2B, const float* M2W, const float* M2B,
    const float* LN3G, const float* LN3B, const float* M3W, const float* M3B,
    float* __restrict__ PTAB) {
  int t = blockIdx.x * 256 + threadIdx.x;
  if (t >= 961) return;
  float g0 = (float)(t / 31) - 15.0f;
  float g1 = (float)(t % 31) - 15.0f;
  float p[11], r[11];
#pragma unroll
  for (int j = 0; j < 11; ++j)
    p[j] = g0 * PPW[j] + g1 * PPW[11 + j] + PPB[j];
  ln_relu11(p, LN1G, LN1B, r);
  mm11(r, M1W, M1B, p);
  ln_relu11(p, LN2G, LN2B, r);
  mm11(r, M2W, M2B, p);
  ln_relu11(p, LN3G, LN3B, r);
#pragma unroll
  for (int h = 0; h < 6; ++h) {
    float s = M3B[h];
#pragma unroll
    for (int j = 0; j < 11; ++j) s += r[j] * M3W[j * 6 + h];
    PTAB[t * 6 + h] = s;
  }
}

// ---------------------------------------------------------------------------
// K5b: RPB[h][l][m] = mean over 2x2 of PTAB[(dr+15)*31+(dc+15)][h]
// ---------------------------------------------------------------------------
__global__ __launch_bounds__(256) void k5b_rpb(const float* __restrict__ PTAB,
                                               float* __restrict__ RPB) {
  int t = blockIdx.x * 256 + threadIdx.x;  // < 98304
  int m = t & 63;
  int l = (t >> 6) & 255;
  int h = t >> 14;
  int mh = m >> 3, mw = m & 7;
  int qr = l >> 4, qc = l & 15;
  float s = 0.f;
#pragma unroll
  for (int rh = 0; rh < 2; ++rh)
#pragma unroll
    for (int rw = 0; rw < 2; ++rw) {
      int dr = qr - (mh * 2 + rh) + 15;
      int dc = qc - (mw * 2 + rw) + 15;
      s += PTAB[(dr * 31 + dc) * 6 + h];
    }
  RPB[t] = 0.25f * s;
}

// ---------------------------------------------------------------------------
// K7a: cc[wi][c][d] = sum_l q[l][c]*v[l][d] / 256, f32 out (true scale).
// ---------------------------------------------------------------------------
__global__ __launch_bounds__(256) void k7a_cc(const __half* __restrict__ QX,
                                              float* __restrict__ CC) {
  __shared__ __half qs[64 * 90];
  __shared__ __half vs[64 * 90];
  int wi = blockIdx.x, t = threadIdx.x;
  int c0 = (t % 15) * 6, d0 = (t / 15) * 6;
  bool act = t < 225;
  float acc[36];
#pragma unroll
  for (int i = 0; i < 36; ++i) acc[i] = 0.f;
  const uint32* G = (const uint32*)(QX + (size_t)wi * 46080);
  uint32* qsw = (uint32*)qs;
  uint32* vsw = (uint32*)vs;
  for (int pass = 0; pass < 4; ++pass) {
    __syncthreads();
    for (int i = t; i < 2880; i += 256) {
      int l = i / 45, k = i % 45;
      int gw = (pass * 64 + l) * 90;
      qsw[l * 45 + k] = G[gw + k];
      vsw[l * 45 + k] = G[gw + 45 + k];
    }
    __syncthreads();
    if (act) {
      for (int l = 0; l < 64; ++l) {
        const __half2* qh = (const __half2*)&qs[l * 90 + c0];
        const __half2* vh = (const __half2*)&vs[l * 90 + d0];
        float a[6], b[6];
#pragma unroll
        for (int k = 0; k < 3; ++k) {
          __half2 x = qh[k];
          a[2 * k] = __low2float(x); a[2 * k + 1] = __high2float(x);
          __half2 y = vh[k];
          b[2 * k] = __low2float(y); b[2 * k + 1] = __high2float(y);
        }
#pragma unroll
        for (int i = 0; i < 6; ++i)
#pragma unroll
          for (int j = 0; j < 6; ++j) acc[i * 6 + j] += a[i] * b[j];
      }
    }
  }
  if (act) {
    const float s = 1.0f / (256.0f * 4096.0f);
#pragma unroll
    for (int i = 0; i < 6; ++i)
#pragma unroll
      for (int j = 0; j < 6; ++j)
        CC[((size_t)(wi * 90 + c0 + i)) * 90 + d0 + j] = acc[i * 6 + j] * s;
  }
}

// ---------------------------------------------------------------------------
// KA (MFMA): per window, per head h:
//   corr^T(64x256) = vp(64x16) x q^T      [mfma_f32_16x16x16f16]
//   corr' = (corr^T * 1/960 + 256*rpb) -> f16 (B-frag layout = C layout!)
//   x_sp^T(16x256) = vpT(16x64) x corr'   [chained over 4 k-tiles]
// x_sp written in place over q-channels as 8192*x_sp (f16).
// ---------------------------------------------------------------------------
__global__ __launch_bounds__(256) void kA_xsp(__half* __restrict__ QX,
                                              const float* __restrict__ RPB,
                                              const float* __restrict__ SLW,
                                              const float* __restrict__ SLB) {
  __shared__ __align__(16) unsigned char SM[80384];
  f16* U   = (f16*)SM;                    // A: v [256][90]; B: qP [256][104]
  f16* vpS = (f16*)(SM + 53248);          // [64][104] m-major (A1 frags)
  f16* vpT = (f16*)(SM + 66560);          // [96][72]  c-major (A2 frags)
  int wi = blockIdx.x, t = threadIdx.x;
  __half* QW = QX + (size_t)wi * 46080;
  const uint32* G = (const uint32*)QW;
  uint32* Uw = (uint32*)U;

  // ---- phase A: stage v rows [256][90] (coalesced u32) ----
  for (int i = t; i < 11520; i += 256) {
    int l = i / 45, k = i % 45;
    Uw[l * 45 + k] = G[l * 90 + 45 + k];
  }
  __syncthreads();
  // ---- build vp in both layouts, x256 scale, c=15 slots = 0 ----
  float w0 = SLW[0], w1 = SLW[1], w2 = SLW[2], w3 = SLW[3];
  float sb = SLB[0];
  for (int e = t; e < 6144; e += 256) {
    int m = e & 63, idx = e >> 6;          // idx = h*16 + c
    int c = idx & 15, h = idx >> 4;
    f16 val = (f16)0;
    if (c < 15) {
      int ch = h * 15 + c;
      int lb = (m >> 3) * 32 + (m & 7) * 2;
      float s = w0 * (float)U[lb * 90 + ch] + w1 * (float)U[(lb + 1) * 90 + ch]
              + w2 * (float)U[(lb + 16) * 90 + ch] + w3 * (float)U[(lb + 17) * 90 + ch];
      val = (f16)(s * 4.f + sb * 256.f);
    }
    vpS[m * 104 + idx] = val;
    vpT[idx * 72 + m] = val;
  }
  __syncthreads();
  // ---- phase B: overwrite U with qP [256][104], 16 c-slots/head ----
  for (int j = t; j < 1536; j += 256) {
    int h = j >> 8, l = j & 255;
    U[l * 104 + h * 16 + 15] = (f16)0;
  }
  for (int i = t; i < 11520; i += 256) {
    int l = i / 45, k = i % 45;
    union { uint32 w; f16 h[2]; } cv;
    cv.w = G[l * 90 + k];
    int cg0 = 2 * k, cg1 = 2 * k + 1;
    int h0 = cg0 / 15, c0 = cg0 - h0 * 15;
    int h1 = cg1 / 15, c1 = cg1 - h1 * 15;
    U[l * 104 + h0 * 16 + c0] = cv.h[0];
    U[l * 104 + h1 * 16 + c1] = cv.h[1];
  }
  __syncthreads();

  int lane = t & 63, w = t >> 6;
  int lm = lane & 15, lq = lane >> 4;
  const float invA = 1.0f / 960.0f;        // 256 / (15*16384)
  for (int h = 0; h < 6; ++h) {
    f16x4 a1[4], b1[4];
#pragma unroll
    for (int mt = 0; mt < 4; ++mt)
      a1[mt] = *(const f16x4*)&vpS[(mt * 16 + lm) * 104 + h * 16 + lq * 4];
#pragma unroll
    for (int lt = 0; lt < 4; ++lt)
      b1[lt] = *(const f16x4*)&U[(w * 64 + lt * 16 + lm) * 104 + h * 16 + lq * 4];
    f32x4 acc1[4][4];
#pragma unroll
    for (int mt = 0; mt < 4; ++mt)
#pragma unroll
      for (int lt = 0; lt < 4; ++lt)
        acc1[mt][lt] = __builtin_amdgcn_mfma_f32_16x16x16f16(
            a1[mt], b1[lt], (f32x4){0.f, 0.f, 0.f, 0.f}, 0, 0, 0);
    // corr' = acc1/960 + 256*rpb  -> f16; C layout == B2 frag layout
    f16x4 b2[4][4];
#pragma unroll
    for (int lt = 0; lt < 4; ++lt) {
      int l = w * 64 + lt * 16 + lm;
      const float* rp = RPB + ((size_t)(h * 256 + l)) * 64;
#pragma unroll
      for (int mt = 0; mt < 4; ++mt) {
        float4 rv = *(const float4*)&rp[mt * 16 + lq * 4];
        f16x4 bb;
        bb[0] = (f16)(acc1[mt][lt][0] * invA + rv.x * 256.f);
        bb[1] = (f16)(acc1[mt][lt][1] * invA + rv.y * 256.f);
        bb[2] = (f16)(acc1[mt][lt][2] * invA + rv.z * 256.f);
        bb[3] = (f16)(acc1[mt][lt][3] * invA + rv.w * 256.f);
        b2[mt][lt] = bb;
      }
    }
    f16x4 a2[4];
#pragma unroll
    for (int kt = 0; kt < 4; ++kt)
      a2[kt] = *(const f16x4*)&vpT[(h * 16 + lm) * 72 + kt * 16 + lq * 4];
#pragma unroll
    for (int lt = 0; lt < 4; ++lt) {
      f32x4 acc2 = (f32x4){0.f, 0.f, 0.f, 0.f};
#pragma unroll
      for (int kt = 0; kt < 4; ++kt)
        acc2 = __builtin_amdgcn_mfma_f32_16x16x16f16(a2[kt], b2[kt][lt], acc2, 0, 0, 0);
      int l = w * 64 + lt * 16 + lm;
      __half* orow = QW + l * 180 + h * 15;
#pragma unroll
      for (int reg = 0; reg < 4; ++reg) {
        int c = lq * 4 + reg;
        if (c < 15) orow[c] = f2h(acc2[reg] * 0.125f);   // 65536*x_sp / 8
      }
    }
  }
}

// ---------------------------------------------------------------------------
// KB (MFMA): x_ch[l][c] = sum_d cc[c][d]*v[l][d], in place over v-channels
// as 8192*x_ch (f16).
// ---------------------------------------------------------------------------
__global__ __launch_bounds__(256) void kB_xch(__half* __restrict__ QX,
                                              const float* __restrict__ CC) {
  __shared__ __align__(16) f16 vA[256 * 104];
  __shared__ __align__(16) f16 ccB[96 * 104];
  int wi = blockIdx.x, t = threadIdx.x;
  __half* QW = QX + (size_t)wi * 46080;
  const uint32* G = (const uint32*)QW;
  uint32* vAw = (uint32*)vA;
  for (int i = t; i < 12288; i += 256) {   // 256 rows x 48 u32 (cols 0..95)
    int l = i / 48, kk = i % 48;
    vAw[l * 52 + kk] = (kk < 45) ? G[l * 90 + 45 + kk] : 0u;
  }
  const float* ccg = CC + (size_t)wi * 8100;
  uint32* ccw = (uint32*)ccB;
  for (int i = t; i < 4992; i += 256) {    // 96 rows x 52 u32, zero pads
    int c = i / 52, dd = i % 52;
    uint32 out = 0u;
    if (c < 90 && dd < 45) {
      float2 f = *(const float2*)&ccg[c * 90 + dd * 2];
      union { uint32 w; f16 h[2]; } cv;
      cv.h[0] = (f16)(f.x * 65536.f);
      cv.h[1] = (f16)(f.y * 65536.f);
      out = cv.w;
    }
    ccw[c * 52 + dd] = out;
  }
  __syncthreads();
  int lane = t & 63, w = t >> 6;
  int lm = lane & 15, lq = lane >> 4;
  f32x4 acc[4][6];
#pragma unroll
  for (int mt = 0; mt < 4; ++mt)
#pragma unroll
    for (int nt = 0; nt < 6; ++nt) acc[mt][nt] = (f32x4){0.f, 0.f, 0.f, 0.f};
  for (int kc = 0; kc < 3; ++kc) {
    f16x8 af[4], bf[6];
#pragma unroll
    for (int mt = 0; mt < 4; ++mt)
      af[mt] = *(const f16x8*)&vA[(w * 64 + mt * 16 + lm) * 104 + kc * 32 + lq * 8];
#pragma unroll
    for (int nt = 0; nt < 6; ++nt)
      bf[nt] = *(const f16x8*)&ccB[(nt * 16 + lm) * 104 + kc * 32 + lq * 8];
#pragma unroll
    for (int mt = 0; mt < 4; ++mt)
#pragma unroll
      for (int nt = 0; nt < 6; ++nt)
        acc[mt][nt] = __builtin_amdgcn_mfma_f32_16x16x32_f16(
            af[mt], bf[nt], acc[mt][nt], 0, 0, 0);
  }
#pragma unroll
  for (int mt = 0; mt < 4; ++mt) {
#pragma unroll
    for (int reg = 0; reg < 4; ++reg) {
      int l = w * 64 + mt * 16 + lq * 4 + reg;
      __half* orow = QW + l * 180 + 90;
#pragma unroll
      for (int nt = 0; nt < 6; ++nt) {
        int c = nt * 16 + lm;
        if (c < 90) orow[c] = f2h(acc[mt][nt][reg] * 0.001953125f);  // 2^22 -> 2^13
      }
    }
  }
}

// ---------------------------------------------------------------------------
// K8 (MFMA, no LDS, no barriers): out = (XS/8192) @ proj_w + proj_b, f32 out,
// window-reverse scatter. A-frags straight from XS (f16), B from PWT table.
// ---------------------------------------------------------------------------
__global__ __launch_bounds__(256) void k8_proj(const __half* __restrict__ XS,
                                               const f16* __restrict__ PWT,
                                               const float* __restrict__ PB,
                                               float* __restrict__ OUT) {
  int t = threadIdx.x;
  int w0r = blockIdx.x * 128;
  int lane = t & 63, wave = t >> 6;
  int lm = lane & 15, lq = lane >> 4;

  // ---- A-fragments in registers ----
  f16x8 ax[6][2];
#pragma unroll
  for (int mt = 0; mt < 2; ++mt) {
    int row = w0r + wave * 32 + mt * 16 + lm;
    const f16* xr = (const f16*)XS + (size_t)row * 180;
#pragma unroll
    for (int ch = 0; ch < 6; ++ch) {
      int k0 = ch * 32 + lq * 8;
      U8 v; v.u4 = (uint4){0u, 0u, 0u, 0u};
      if (k0 + 8 <= 180) {
        v.u2[0] = *(const uint2*)&xr[k0];
        v.u2[1] = *(const uint2*)&xr[k0 + 4];
      } else if (k0 < 180) {  // k0 == 176
        v.u2[0] = *(const uint2*)&xr[k0];
      }
      ax[ch][mt] = v.v;
    }
  }

  for (int bn = 0; bn < 4; ++bn) {
    int n0 = bn * 48;
    f32x4 acc[2][3];
#pragma unroll
    for (int i = 0; i < 2; ++i)
#pragma unroll
      for (int j = 0; j < 3; ++j) acc[i][j] = (f32x4){0.f, 0.f, 0.f, 0.f};

#pragma unroll
    for (int ch = 0; ch < 6; ++ch) {
#pragma unroll
      for (int nt = 0; nt < 3; ++nt) {
        int n = n0 + nt * 16 + lm;
        f16x8 bf = *(const f16x8*)&PWT[n * 192 + ch * 32 + lq * 8];
        acc[0][nt] = __builtin_amdgcn_mfma_f32_16x16x32_f16(
            ax[ch][0], bf, acc[0][nt], 0, 0, 0);
        acc[1][nt] = __builtin_amdgcn_mfma_f32_16x16x32_f16(
            ax[ch][1], bf, acc[1][nt], 0, 0, 0);
      }
    }

    float pb[3];
#pragma unroll
    for (int nt = 0; nt < 3; ++nt) {
      int col = n0 + nt * 16 + lm;
      pb[nt] = (col < 180) ? PB[col] : 0.f;
    }
    const float inv = 1.0f / 8192.0f;
#pragma unroll
    for (int mt = 0; mt < 2; ++mt) {
#pragma unroll
      for (int reg = 0; reg < 4; ++reg) {
        int w = w0r + wave * 32 + mt * 16 + lq * 4 + reg;
        int wi = w >> 8, l = w & 255;
        int b = wi >> 8, wy = (wi >> 4) & 15, wx = wi & 15;
        int ly = l >> 4, lx = l & 15;
        int p = (b << 16) | (((wy << 4) | ly) << 8) | ((wx << 4) | lx);
        float* orow = OUT + (size_t)p * 180;
#pragma unroll
        for (int nt = 0; nt < 3; ++nt) {
          int col = n0 + nt * 16 + lm;
          if (col < 180) orow[col] = acc[mt][nt][reg] * inv + pb[nt];
        }
      }
    }
  }
}

// ---------------------------------------------------------------------------
// Workspace layout (bytes) — peak requirement 66,060,288 (63.0 MB):
//  QX  f16 [512][256][180]  @ 0            (47,185,920)  qv*64 -> XS in place
//  T1  f16 [131072][36]     @ 47,185,920   ( 9,437,184)  dead after k2
//  T2  f16 [131072][36]     @ 56,623,104   ( 9,437,184)  dead after k3
//  PTAB f32 [961*6]         @ 47,185,920   over dead T1
//  RPB  f32 [6][256][64]    @ 47,212,544   over dead T1 (ends 47,605,760)
//  WT3  f16 [192][40]       @ 47,605,760   (15,360)  written k0_wt (post-k2),
//  WTD  f16 [192][192]      @ 47,621,120   (73,728)  dead after k3; CC
//                                                    overwrites both (k7a)
//  CC   f32 [512][90][90]   @ 47,605,760   (16,588,800, ends 64,194,560)
//  PWT  f16 [192][192]      @ 64,194,560   (73,728)  written k0_pw (post-k3,
//                                                    over dead T2 tail)
// ---------------------------------------------------------------------------
extern "C" void kernel_launch(void* const* d_in, const int* in_sizes, int n_in,
                              void* d_out, int out_size, void* d_ws, size_t ws_size,
                              hipStream_t stream) {
  const float* X    = (const float*)d_in[0];
  const float* W1   = (const float*)d_in[1];
  const float* B1   = (const float*)d_in[2];
  const float* W2   = (const float*)d_in[3];
  const float* B2   = (const float*)d_in[4];
  const float* W3   = (const float*)d_in[5];
  const float* B3c  = (const float*)d_in[6];
  const float* WD   = (const float*)d_in[7];
  const float* BD   = (const float*)d_in[8];
  const float* SLW  = (const float*)d_in[9];
  const float* SLB  = (const float*)d_in[10];
  const float* PPW  = (const float*)d_in[11];
  const float* PPB  = (const float*)d_in[12];
  const float* LN1G = (const float*)d_in[13];
  const float* LN1B = (const float*)d_in[14];
  const float* M1W  = (const float*)d_in[15];
  const float* M1B  = (const float*)d_in[16];
  const float* LN2G = (const float*)d_in[17];
  const float* LN2B = (const float*)d_in[18];
  const float* M2W  = (const float*)d_in[19];
  const float* M2B  = (const float*)d_in[20];
  const float* LN3G = (const float*)d_in[21];
  const float* LN3B = (const float*)d_in[22];
  const float* M3W  = (const float*)d_in[23];
  const float* M3B  = (const float*)d_in[24];
  const float* PW   = (const float*)d_in[25];
  const float* PB   = (const float*)d_in[26];
  float* OUT = (float*)d_out;

  char* ws = (char*)d_ws;
  __half* QX  = (__half*)(ws);
  __half* T1  = (__half*)(ws + 47185920);
  __half* T2  = (__half*)(ws + 56623104);
  float* PTAB = (float*)(ws + 47185920);
  float* RPB  = (float*)(ws + 47212544);
  f16*   WT3  = (f16*)(ws + 47605760);
  f16*   WTD  = (f16*)(ws + 47621120);
  float* CC   = (float*)(ws + 47605760);
  f16*   PWT  = (f16*)(ws + 64194560);

  hipLaunchKernelGGL(k1_conv1, dim3(1024), dim3(256), 0, stream, X, W1, B1, T1);
  hipLaunchKernelGGL(k2_conv2, dim3(2048), dim3(256), 0, stream, T1, W2, B2, T2);
  hipLaunchKernelGGL(k0_wt, dim3(144), dim3(256), 0, stream, W3, WD, WT3, WTD);
  hipLaunchKernelGGL(k3_qv, dim3(1024), dim3(256), 0, stream, X, T2, WT3, WTD, B3c, BD, QX);
  hipLaunchKernelGGL(k0_pw, dim3(144), dim3(256), 0, stream, PW, PWT);
  hipLaunchKernelGGL(k5a_posmlp, dim3(4), dim3(256), 0, stream,
                     PPW, PPB, LN1G, LN1B, M1W, M1B, LN2G, LN2B, M2W, M2B,
                     LN3G, LN3B, M3W, M3B, PTAB);
  hipLaunchKernelGGL(k5b_rpb, dim3(384), dim3(256), 0, stream, PTAB, RPB);
  hipLaunchKernelGGL(k7a_cc, dim3(512), dim3(256), 0, stream, QX, CC);
  hipLaunchKernelGGL(kA_xsp, dim3(512), dim3(256), 0, stream, QX, RPB, SLW, SLB);
  hipLaunchKernelGGL(kB_xch, dim3(512), dim3(256), 0, stream, QX, CC);
  hipLaunchKernelGGL(k8_proj, dim3(1024), dim3(256), 0, stream, QX, PWT, PB, OUT);
}

// Round 5
// 542.002 us; speedup vs baseline: 1.4800x; 1.1320x over previous
//
#include <hip/hip_runtime.h>
#include <hip/hip_fp16.h>

typedef unsigned int uint32;
typedef _Float16 f16;
typedef f16 f16x4 __attribute__((ext_vector_type(4)));
typedef f16 f16x8 __attribute__((ext_vector_type(8)));
typedef float f32x4 __attribute__((ext_vector_type(4)));

union U8 { f16x8 v; uint4 u4; uint2 u2[2]; f16 h[8]; };

__device__ __forceinline__ float h2f(__half v) { return __half2float(v); }
__device__ __forceinline__ __half f2h(float v) { return __float2half(v); }

// ---------------------------------------------------------------------------
// K1: t1 = leaky_relu(x @ conv1_w + conv1_b)  (131072,180)->(131072,36) f16
// ---------------------------------------------------------------------------
__global__ __launch_bounds__(256) void k1_conv1(const float* __restrict__ X,
                                                const float* __restrict__ W1,
                                                const float* __restrict__ B1,
                                                __half* __restrict__ T1) {
  __shared__ float sm[60 * 132 + 60 * 36];
  float* Xt = sm;              // [60][132] (128 + pad4), k-major
  float* Ws = sm + 60 * 132;   // [60][36]
  int t = threadIdx.x;
  int p0 = blockIdx.x * 128;
  bool act = t < 144;
  int r0 = (t / 9) * 4, c0 = (t % 9) * 4;
  float acc[2][16];
#pragma unroll
  for (int h = 0; h < 2; ++h)
#pragma unroll
    for (int i = 0; i < 16; ++i) acc[h][i] = 0.f;

  for (int chunk = 0; chunk < 3; ++chunk) {
    __syncthreads();
    int kc = chunk * 60;
    for (int i = t; i < 128 * 60; i += 256) {
      int m = i / 60, k = i % 60;
      Xt[k * 132 + m] = X[(size_t)(p0 + m) * 180 + kc + k];
    }
    for (int i = t; i < 60 * 36; i += 256) {
      int k = i / 36, c = i % 36;
      Ws[k * 36 + c] = W1[(kc + k) * 36 + c];
    }
    __syncthreads();
    if (act) {
      for (int k = 0; k < 60; ++k) {
        float4 a0 = *(const float4*)&Xt[k * 132 + r0];
        float4 a1 = *(const float4*)&Xt[k * 132 + r0 + 64];
        float4 b  = *(const float4*)&Ws[k * 36 + c0];
        float av0[4] = {a0.x, a0.y, a0.z, a0.w};
        float av1[4] = {a1.x, a1.y, a1.z, a1.w};
        float bv[4]  = {b.x, b.y, b.z, b.w};
#pragma unroll
        for (int i = 0; i < 4; ++i)
#pragma unroll
          for (int j = 0; j < 4; ++j) {
            acc[0][i * 4 + j] += av0[i] * bv[j];
            acc[1][i * 4 + j] += av1[i] * bv[j];
          }
      }
    }
  }
  if (!act) return;
  float bb[4];
#pragma unroll
  for (int i = 0; i < 4; ++i) bb[i] = B1[c0 + i];
#pragma unroll
  for (int h = 0; h < 2; ++h)
#pragma unroll
    for (int ri = 0; ri < 4; ++ri) {
      int p = p0 + h * 64 + r0 + ri;
      __half* o = T1 + (size_t)p * 36 + c0;
      __half2 h01, h23;
      float v0 = acc[h][ri * 4 + 0] + bb[0];
      float v1 = acc[h][ri * 4 + 1] + bb[1];
      float v2 = acc[h][ri * 4 + 2] + bb[2];
      float v3 = acc[h][ri * 4 + 3] + bb[3];
      h01.x = f2h(v0 > 0.f ? v0 : 0.2f * v0);
      h01.y = f2h(v1 > 0.f ? v1 : 0.2f * v1);
      h23.x = f2h(v2 > 0.f ? v2 : 0.2f * v2);
      h23.y = f2h(v3 > 0.f ? v3 : 0.2f * v3);
      *(__half2*)o = h01;
      *(__half2*)(o + 2) = h23;
    }
}

// ---------------------------------------------------------------------------
// K0_w2: conv2_w -> W2T[9][48][40] f16, n-major per tap, zero-padded.
// W2T[(tap*48+n)*40+k] = W2[(tap*36+k)*36+n] for n<36,k<36 else 0.
// Lives at ws+0 (QX region, dead until k3). Launched before k2.
// ---------------------------------------------------------------------------
__global__ __launch_bounds__(256) void k0_w2(const float* __restrict__ W2,
                                             f16* __restrict__ W2T) {
  int i = blockIdx.x * 256 + threadIdx.x;
  if (i < 17280) {
    int tap = i / 1920, rem = i % 1920, n = rem / 40, k = rem % 40;
    W2T[i] = (n < 36 && k < 36) ? (f16)W2[(tap * 36 + k) * 36 + n] : (f16)0;
  }
}

// ---------------------------------------------------------------------------
// K2 (MFMA implicit GEMM): t2 = leaky_relu(conv3x3(t1)+b2). Block = 128-px
// row strip; ins[3][132][40] f16 staged once (one barrier); per tap (kh,kw)
// A-frag = shifted ins row, B-frag = 16B load from L2-resident W2T.
// 9 taps x 2 k-chunks x 2 mt x 3 nt = 108 MFMA/wave.
// ---------------------------------------------------------------------------
__global__ __launch_bounds__(256) void k2_conv2(const __half* __restrict__ T1,
                                                const f16* __restrict__ W2T,
                                                const float* __restrict__ B2,
                                                __half* __restrict__ T2) {
  __shared__ __align__(16) f16 ins[3 * 132 * 40];  // [kh][xx][ci40]
  int t = threadIdx.x;
  int p0 = blockIdx.x * 128;
  int b = p0 >> 16, y = (p0 >> 8) & 255, x0 = p0 & 255;

  const uint32* T1u = (const uint32*)T1;   // rows are 18 u32
  uint32* insu = (uint32*)ins;             // [kh][xx][20 u32]
  for (int i = t; i < 7920; i += 256) {    // 3*132*20
    int kh = i / 2640, rem = i % 2640;
    int xx = rem / 20, u = rem % 20;
    int ry = y + kh - 1, gx = x0 + xx - 1;
    uint32 v = 0u;
    if (u < 18 && xx < 130 && (unsigned)ry < 256u && (unsigned)gx < 256u)
      v = T1u[((size_t)((b * 256 + ry) * 256 + gx)) * 18 + u];
    insu[i] = v;                           // i == (kh*132+xx)*20+u
  }
  __syncthreads();

  int lane = t & 63, wave = t >> 6;
  int lm = lane & 15, lq = lane >> 4;
  const f16x8 zero8 = {(f16)0,(f16)0,(f16)0,(f16)0,(f16)0,(f16)0,(f16)0,(f16)0};

  f32x4 acc[2][3];
#pragma unroll
  for (int mt = 0; mt < 2; ++mt)
#pragma unroll
    for (int nt = 0; nt < 3; ++nt) acc[mt][nt] = (f32x4){0.f, 0.f, 0.f, 0.f};

#pragma unroll
  for (int kh = 0; kh < 3; ++kh) {
#pragma unroll
    for (int kw = 0; kw < 3; ++kw) {
      int tap = kh * 3 + kw;
      f16x8 a0[2], a1[2];
#pragma unroll
      for (int mt = 0; mt < 2; ++mt) {
        int xx = wave * 32 + mt * 16 + lm + kw;   // <= 129
        const f16* ar = &ins[(kh * 132 + xx) * 40];
        a0[mt] = *(const f16x8*)&ar[lq * 8];
        a1[mt] = (lq == 0) ? *(const f16x8*)&ar[32] : zero8;
      }
#pragma unroll
      for (int nt = 0; nt < 3; ++nt) {
        const f16* br = &W2T[(tap * 48 + nt * 16 + lm) * 40];
        f16x8 b0 = *(const f16x8*)&br[lq * 8];
        f16x8 b1 = (lq == 0) ? *(const f16x8*)&br[32] : zero8;
#pragma unroll
        for (int mt = 0; mt < 2; ++mt) {
          acc[mt][nt] = __builtin_amdgcn_mfma_f32_16x16x32_f16(
              a0[mt], b0, acc[mt][nt], 0, 0, 0);
          acc[mt][nt] = __builtin_amdgcn_mfma_f32_16x16x32_f16(
              a1[mt], b1, acc[mt][nt], 0, 0, 0);
        }
      }
    }
  }

  float bb[3];
#pragma unroll
  for (int nt = 0; nt < 3; ++nt) {
    int co = nt * 16 + lm;
    bb[nt] = (co < 36) ? B2[co] : 0.f;
  }
#pragma unroll
  for (int mt = 0; mt < 2; ++mt) {
#pragma unroll
    for (int reg = 0; reg < 4; ++reg) {
      int p = p0 + wave * 32 + mt * 16 + lq * 4 + reg;
      __half* o = T2 + (size_t)p * 36;
#pragma unroll
      for (int nt = 0; nt < 3; ++nt) {
        int co = nt * 16 + lm;
        if (co < 36) {
          float v = acc[mt][nt][reg] + bb[nt];
          o[co] = f2h(v > 0.f ? v : 0.2f * v);
        }
      }
    }
  }
}

// ---------------------------------------------------------------------------
// K0_wt: transpose+convert W3/WD to n-major f16 tables with zero padding.
// ---------------------------------------------------------------------------
__global__ __launch_bounds__(256) void k0_wt(const float* __restrict__ SW3,
                                             const float* __restrict__ SWD,
                                             f16* __restrict__ WT3,
                                             f16* __restrict__ WTD) {
  int tid = blockIdx.x * 256 + threadIdx.x;
  int stride = gridDim.x * 256;
  for (int i = tid; i < 192 * 40; i += stride) {
    int n = i / 40, k = i % 40;
    WT3[i] = (n < 180 && k < 36) ? (f16)SW3[k * 180 + n] : (f16)0;
  }
  for (int i = tid; i < 192 * 192; i += stride) {
    int n = i / 192, k = i % 192;
    WTD[i] = (n < 180 && k < 180) ? (f16)SWD[k * 180 + n] : (f16)0;
  }
}

// K0_pw: same for proj_w -> PWT[192][192]. Launched AFTER k3 (lives over T2).
__global__ __launch_bounds__(256) void k0_pw(const float* __restrict__ SPW,
                                             f16* __restrict__ PWT) {
  int tid = blockIdx.x * 256 + threadIdx.x;
  int stride = gridDim.x * 256;
  for (int i = tid; i < 192 * 192; i += stride) {
    int n = i / 192, k = i % 192;
    PWT[i] = (n < 180 && k < 180) ? (f16)SPW[k * 180 + n] : (f16)0;
  }
}

// ---------------------------------------------------------------------------
// K3 (MFMA, no LDS, no barriers): qv = (t2@W3+b3)*(x@WD+bd), x64 f16,
// windowed scatter. A-frags in registers; B-frags from L2 tables.
// ---------------------------------------------------------------------------
__global__ __launch_bounds__(256) void k3_qv(const float* __restrict__ X,
                                             const __half* __restrict__ T2,
                                             const f16* __restrict__ WT3,
                                             const f16* __restrict__ WTD,
                                             const float* __restrict__ B3,
                                             const float* __restrict__ BD,
                                             __half* __restrict__ QX) {
  int t = threadIdx.x;
  int p0 = blockIdx.x * 128;
  int lane = t & 63, wave = t >> 6;
  int lm = lane & 15, lq = lane >> 4;

  const f16x8 zero8 = {(f16)0,(f16)0,(f16)0,(f16)0,(f16)0,(f16)0,(f16)0,(f16)0};

  f16x8 ax[6][2];
  f16x8 at0[2];
  f16x8 at1[2];
#pragma unroll
  for (int mt = 0; mt < 2; ++mt) {
    int row = p0 + wave * 32 + mt * 16 + lm;
    const float* xr = X + (size_t)row * 180;
#pragma unroll
    for (int ch = 0; ch < 6; ++ch) {
      int k0 = ch * 32 + lq * 8;
      U8 v; v.u4 = (uint4){0u, 0u, 0u, 0u};
      if (k0 + 8 <= 180) {
        float4 a = *(const float4*)&xr[k0];
        float4 b = *(const float4*)&xr[k0 + 4];
        v.h[0]=(f16)a.x; v.h[1]=(f16)a.y; v.h[2]=(f16)a.z; v.h[3]=(f16)a.w;
        v.h[4]=(f16)b.x; v.h[5]=(f16)b.y; v.h[6]=(f16)b.z; v.h[7]=(f16)b.w;
      } else if (k0 < 180) {  // k0 == 176
        float4 a = *(const float4*)&xr[k0];
        v.h[0]=(f16)a.x; v.h[1]=(f16)a.y; v.h[2]=(f16)a.z; v.h[3]=(f16)a.w;
      }
      ax[ch][mt] = v.v;
    }
    const f16* tr = (const f16*)T2 + (size_t)row * 36;
    U8 tv;
    tv.u2[0] = *(const uint2*)&tr[lq * 8];
    tv.u2[1] = *(const uint2*)&tr[lq * 8 + 4];
    at0[mt] = tv.v;
    U8 t1v; t1v.u4 = (uint4){0u, 0u, 0u, 0u};
    if (lq == 0) t1v.u2[0] = *(const uint2*)&tr[32];
    at1[mt] = t1v.v;
  }

  for (int bn = 0; bn < 4; ++bn) {
    int n0 = bn * 48;
    f32x4 accC[2][3], accD[2][3];
#pragma unroll
    for (int i = 0; i < 2; ++i)
#pragma unroll
      for (int j = 0; j < 3; ++j) {
        accC[i][j] = (f32x4){0.f, 0.f, 0.f, 0.f};
        accD[i][j] = (f32x4){0.f, 0.f, 0.f, 0.f};
      }

#pragma unroll
    for (int nt = 0; nt < 3; ++nt) {
      int n = n0 + nt * 16 + lm;
      f16x8 b0 = *(const f16x8*)&WT3[n * 40 + lq * 8];
      f16x8 b1 = (lq == 0) ? *(const f16x8*)&WT3[n * 40 + 32] : zero8;
#pragma unroll
      for (int mt = 0; mt < 2; ++mt) {
        accC[mt][nt] = __builtin_amdgcn_mfma_f32_16x16x32_f16(
            at0[mt], b0, accC[mt][nt], 0, 0, 0);
        accC[mt][nt] = __builtin_amdgcn_mfma_f32_16x16x32_f16(
            at1[mt], b1, accC[mt][nt], 0, 0, 0);
      }
    }

#pragma unroll
    for (int ch = 0; ch < 6; ++ch) {
#pragma unroll
      for (int nt = 0; nt < 3; ++nt) {
        int n = n0 + nt * 16 + lm;
        f16x8 bf = *(const f16x8*)&WTD[n * 192 + ch * 32 + lq * 8];
        accD[0][nt] = __builtin_amdgcn_mfma_f32_16x16x32_f16(
            ax[ch][0], bf, accD[0][nt], 0, 0, 0);
        accD[1][nt] = __builtin_amdgcn_mfma_f32_16x16x32_f16(
            ax[ch][1], bf, accD[1][nt], 0, 0, 0);
      }
    }

    float cb[3], db[3];
#pragma unroll
    for (int nt = 0; nt < 3; ++nt) {
      int col = n0 + nt * 16 + lm;
      cb[nt] = (col < 180) ? B3[col] : 0.f;
      db[nt] = (col < 180) ? BD[col] : 0.f;
    }
#pragma unroll
    for (int mt = 0; mt < 2; ++mt) {
#pragma unroll
      for (int reg = 0; reg < 4; ++reg) {
        int p = p0 + wave * 32 + mt * 16 + lq * 4 + reg;
        int b = p >> 16, y = (p >> 8) & 255, x = p & 255;
        int wi = (b << 8) | ((y >> 4) << 4) | (x >> 4);
        int l = ((y & 15) << 4) | (x & 15);
        __half* orow = QX + ((size_t)(wi * 256 + l)) * 180;
#pragma unroll
        for (int nt = 0; nt < 3; ++nt) {
          int col = n0 + nt * 16 + lm;
          if (col < 180)
            orow[col] = f2h((accC[mt][nt][reg] + cb[nt]) *
                            (accD[mt][nt][reg] + db[nt]) * 64.f);
        }
      }
    }
  }
}

// ---------------------------------------------------------------------------
// K5a: position-bias MLP over 961 grid points -> PTAB[961][6] f32
// ---------------------------------------------------------------------------
__device__ __forceinline__ void ln_relu11(const float* p, const float* g,
                                          const float* b, float* r) {
  float m = 0.f;
#pragma unroll
  for (int j = 0; j < 11; ++j) m += p[j];
  m *= (1.0f / 11.0f);
  float v = 0.f;
#pragma unroll
  for (int j = 0; j < 11; ++j) { float d = p[j] - m; v += d * d; }
  v *= (1.0f / 11.0f);
  float inv = 1.0f / sqrtf(v + 1e-5f);
#pragma unroll
  for (int j = 0; j < 11; ++j) {
    float xn = (p[j] - m) * inv * g[j] + b[j];
    r[j] = fmaxf(xn, 0.f);
  }
}
__device__ __forceinline__ void mm11(const float* r, const float* W,
                                     const float* b, float* o) {
#pragma unroll
  for (int j2 = 0; j2 < 11; ++j2) {
    float s = b[j2];
#pragma unroll
    for (int j = 0; j < 11; ++j) s += r[j] * W[j * 11 + j2];
    o[j2] = s;
  }
}

__global__ __launch_bounds__(256) void k5a_posmlp(
    const float* PPW, const float* PPB,
    const float* LN1G, const float* LN1B, const float* M1W, const float* M1B,
    const float* LN2G, const float* LN2B, const float* M2W, const float* M2B,
    const float* LN3G, const float* LN3B, const float* M3W, const float* M3B,
    float* __restrict__ PTAB) {
  int t = blockIdx.x * 256 + threadIdx.x;
  if (t >= 961) return;
  float g0 = (float)(t / 31) - 15.0f;
  float g1 = (float)(t % 31) - 15.0f;
  float p[11], r[11];
#pragma unroll
  for (int j = 0; j < 11; ++j)
    p[j] = g0 * PPW[j] + g1 * PPW[11 + j] + PPB[j];
  ln_relu11(p, LN1G, LN1B, r);
  mm11(r, M1W, M1B, p);
  ln_relu11(p, LN2G, LN2B, r);
  mm11(r, M2W, M2B, p);
  ln_relu11(p, LN3G, LN3B, r);
#pragma unroll
  for (int h = 0; h < 6; ++h) {
    float s = M3B[h];
#pragma unroll
    for (int j = 0; j < 11; ++j) s += r[j] * M3W[j * 6 + h];
    PTAB[t * 6 + h] = s;
  }
}

// ---------------------------------------------------------------------------
// K5b: RPB[h][l][m] = mean over 2x2 of PTAB[(dr+15)*31+(dc+15)][h]
// ---------------------------------------------------------------------------
__global__ __launch_bounds__(256) void k5b_rpb(const float* __restrict__ PTAB,
                                               float* __restrict__ RPB) {
  int t = blockIdx.x * 256 + threadIdx.x;  // < 98304
  int m = t & 63;
  int l = (t >> 6) & 255;
  int h = t >> 14;
  int mh = m >> 3, mw = m & 7;
  int qr = l >> 4, qc = l & 15;
  float s = 0.f;
#pragma unroll
  for (int rh = 0; rh < 2; ++rh)
#pragma unroll
    for (int rw = 0; rw < 2; ++rw) {
      int dr = qr - (mh * 2 + rh) + 15;
      int dc = qc - (mw * 2 + rw) + 15;
      s += PTAB[(dr * 31 + dc) * 6 + h];
    }
  RPB[t] = 0.25f * s;
}

// ---------------------------------------------------------------------------
// K7a: cc[wi][c][d] = sum_l q[l][c]*v[l][d] / 256, f32 out (true scale).
// ---------------------------------------------------------------------------
__global__ __launch_bounds__(256) void k7a_cc(const __half* __restrict__ QX,
                                              float* __restrict__ CC) {
  __shared__ __half qs[64 * 90];
  __shared__ __half vs[64 * 90];
  int wi = blockIdx.x, t = threadIdx.x;
  int c0 = (t % 15) * 6, d0 = (t / 15) * 6;
  bool act = t < 225;
  float acc[36];
#pragma unroll
  for (int i = 0; i < 36; ++i) acc[i] = 0.f;
  const uint32* G = (const uint32*)(QX + (size_t)wi * 46080);
  uint32* qsw = (uint32*)qs;
  uint32* vsw = (uint32*)vs;
  for (int pass = 0; pass < 4; ++pass) {
    __syncthreads();
    for (int i = t; i < 2880; i += 256) {
      int l = i / 45, k = i % 45;
      int gw = (pass * 64 + l) * 90;
      qsw[l * 45 + k] = G[gw + k];
      vsw[l * 45 + k] = G[gw + 45 + k];
    }
    __syncthreads();
    if (act) {
      for (int l = 0; l < 64; ++l) {
        const __half2* qh = (const __half2*)&qs[l * 90 + c0];
        const __half2* vh = (const __half2*)&vs[l * 90 + d0];
        float a[6], b[6];
#pragma unroll
        for (int k = 0; k < 3; ++k) {
          __half2 x = qh[k];
          a[2 * k] = __low2float(x); a[2 * k + 1] = __high2float(x);
          __half2 y = vh[k];
          b[2 * k] = __low2float(y); b[2 * k + 1] = __high2float(y);
        }
#pragma unroll
        for (int i = 0; i < 6; ++i)
#pragma unroll
          for (int j = 0; j < 6; ++j) acc[i * 6 + j] += a[i] * b[j];
      }
    }
  }
  if (act) {
    const float s = 1.0f / (256.0f * 4096.0f);
#pragma unroll
    for (int i = 0; i < 6; ++i)
#pragma unroll
      for (int j = 0; j < 6; ++j)
        CC[((size_t)(wi * 90 + c0 + i)) * 90 + d0 + j] = acc[i * 6 + j] * s;
  }
}

// ---------------------------------------------------------------------------
// KA (MFMA): per window, per head h:
//   corr^T(64x256) = vp(64x16) x q^T      [mfma_f32_16x16x16f16]
//   corr' = (corr^T * 1/960 + 256*rpb) -> f16 (B-frag layout = C layout!)
//   x_sp^T(16x256) = vpT(16x64) x corr'   [chained over 4 k-tiles]
// x_sp written in place over q-channels as 8192*x_sp (f16).
// ---------------------------------------------------------------------------
__global__ __launch_bounds__(256) void kA_xsp(__half* __restrict__ QX,
                                              const float* __restrict__ RPB,
                                              const float* __restrict__ SLW,
                                              const float* __restrict__ SLB) {
  __shared__ __align__(16) unsigned char SM[80384];
  f16* U   = (f16*)SM;                    // A: v [256][90]; B: qP [256][104]
  f16* vpS = (f16*)(SM + 53248);          // [64][104] m-major (A1 frags)
  f16* vpT = (f16*)(SM + 66560);          // [96][72]  c-major (A2 frags)
  int wi = blockIdx.x, t = threadIdx.x;
  __half* QW = QX + (size_t)wi * 46080;
  const uint32* G = (const uint32*)QW;
  uint32* Uw = (uint32*)U;

  for (int i = t; i < 11520; i += 256) {
    int l = i / 45, k = i % 45;
    Uw[l * 45 + k] = G[l * 90 + 45 + k];
  }
  __syncthreads();
  float w0 = SLW[0], w1 = SLW[1], w2 = SLW[2], w3 = SLW[3];
  float sb = SLB[0];
  for (int e = t; e < 6144; e += 256) {
    int m = e & 63, idx = e >> 6;          // idx = h*16 + c
    int c = idx & 15, h = idx >> 4;
    f16 val = (f16)0;
    if (c < 15) {
      int ch = h * 15 + c;
      int lb = (m >> 3) * 32 + (m & 7) * 2;
      float s = w0 * (float)U[lb * 90 + ch] + w1 * (float)U[(lb + 1) * 90 + ch]
              + w2 * (float)U[(lb + 16) * 90 + ch] + w3 * (float)U[(lb + 17) * 90 + ch];
      val = (f16)(s * 4.f + sb * 256.f);
    }
    vpS[m * 104 + idx] = val;
    vpT[idx * 72 + m] = val;
  }
  __syncthreads();
  for (int j = t; j < 1536; j += 256) {
    int h = j >> 8, l = j & 255;
    U[l * 104 + h * 16 + 15] = (f16)0;
  }
  for (int i = t; i < 11520; i += 256) {
    int l = i / 45, k = i % 45;
    union { uint32 w; f16 h[2]; } cv;
    cv.w = G[l * 90 + k];
    int cg0 = 2 * k, cg1 = 2 * k + 1;
    int h0 = cg0 / 15, c0 = cg0 - h0 * 15;
    int h1 = cg1 / 15, c1 = cg1 - h1 * 15;
    U[l * 104 + h0 * 16 + c0] = cv.h[0];
    U[l * 104 + h1 * 16 + c1] = cv.h[1];
  }
  __syncthreads();

  int lane = t & 63, w = t >> 6;
  int lm = lane & 15, lq = lane >> 4;
  const float invA = 1.0f / 960.0f;        // 256 / (15*16384)
  for (int h = 0; h < 6; ++h) {
    f16x4 a1[4], b1[4];
#pragma unroll
    for (int mt = 0; mt < 4; ++mt)
      a1[mt] = *(const f16x4*)&vpS[(mt * 16 + lm) * 104 + h * 16 + lq * 4];
#pragma unroll
    for (int lt = 0; lt < 4; ++lt)
      b1[lt] = *(const f16x4*)&U[(w * 64 + lt * 16 + lm) * 104 + h * 16 + lq * 4];
    f32x4 acc1[4][4];
#pragma unroll
    for (int mt = 0; mt < 4; ++mt)
#pragma unroll
      for (int lt = 0; lt < 4; ++lt)
        acc1[mt][lt] = __builtin_amdgcn_mfma_f32_16x16x16f16(
            a1[mt], b1[lt], (f32x4){0.f, 0.f, 0.f, 0.f}, 0, 0, 0);
    f16x4 b2[4][4];
#pragma unroll
    for (int lt = 0; lt < 4; ++lt) {
      int l = w * 64 + lt * 16 + lm;
      const float* rp = RPB + ((size_t)(h * 256 + l)) * 64;
#pragma unroll
      for (int mt = 0; mt < 4; ++mt) {
        float4 rv = *(const float4*)&rp[mt * 16 + lq * 4];
        f16x4 bb;
        bb[0] = (f16)(acc1[mt][lt][0] * invA + rv.x * 256.f);
        bb[1] = (f16)(acc1[mt][lt][1] * invA + rv.y * 256.f);
        bb[2] = (f16)(acc1[mt][lt][2] * invA + rv.z * 256.f);
        bb[3] = (f16)(acc1[mt][lt][3] * invA + rv.w * 256.f);
        b2[mt][lt] = bb;
      }
    }
    f16x4 a2[4];
#pragma unroll
    for (int kt = 0; kt < 4; ++kt)
      a2[kt] = *(const f16x4*)&vpT[(h * 16 + lm) * 72 + kt * 16 + lq * 4];
#pragma unroll
    for (int lt = 0; lt < 4; ++lt) {
      f32x4 acc2 = (f32x4){0.f, 0.f, 0.f, 0.f};
#pragma unroll
      for (int kt = 0; kt < 4; ++kt)
        acc2 = __builtin_amdgcn_mfma_f32_16x16x16f16(a2[kt], b2[kt][lt], acc2, 0, 0, 0);
      int l = w * 64 + lt * 16 + lm;
      __half* orow = QW + l * 180 + h * 15;
#pragma unroll
      for (int reg = 0; reg < 4; ++reg) {
        int c = lq * 4 + reg;
        if (c < 15) orow[c] = f2h(acc2[reg] * 0.125f);   // 65536*x_sp / 8
      }
    }
  }
}

// ---------------------------------------------------------------------------
// KB (MFMA): x_ch[l][c] = sum_d cc[c][d]*v[l][d], in place over v-channels
// as 8192*x_ch (f16).
// ---------------------------------------------------------------------------
__global__ __launch_bounds__(256) void kB_xch(__half* __restrict__ QX,
                                              const float* __restrict__ CC) {
  __shared__ __align__(16) f16 vA[256 * 104];
  __shared__ __align__(16) f16 ccB[96 * 104];
  int wi = blockIdx.x, t = threadIdx.x;
  __half* QW = QX + (size_t)wi * 46080;
  const uint32* G = (const uint32*)QW;
  uint32* vAw = (uint32*)vA;
  for (int i = t; i < 12288; i += 256) {   // 256 rows x 48 u32 (cols 0..95)
    int l = i / 48, kk = i % 48;
    vAw[l * 52 + kk] = (kk < 45) ? G[l * 90 + 45 + kk] : 0u;
  }
  const float* ccg = CC + (size_t)wi * 8100;
  uint32* ccw = (uint32*)ccB;
  for (int i = t; i < 4992; i += 256) {    // 96 rows x 52 u32, zero pads
    int c = i / 52, dd = i % 52;
    uint32 out = 0u;
    if (c < 90 && dd < 45) {
      float2 f = *(const float2*)&ccg[c * 90 + dd * 2];
      union { uint32 w; f16 h[2]; } cv;
      cv.h[0] = (f16)(f.x * 65536.f);
      cv.h[1] = (f16)(f.y * 65536.f);
      out = cv.w;
    }
    ccw[c * 52 + dd] = out;
  }
  __syncthreads();
  int lane = t & 63, w = t >> 6;
  int lm = lane & 15, lq = lane >> 4;
  f32x4 acc[4][6];
#pragma unroll
  for (int mt = 0; mt < 4; ++mt)
#pragma unroll
    for (int nt = 0; nt < 6; ++nt) acc[mt][nt] = (f32x4){0.f, 0.f, 0.f, 0.f};
  for (int kc = 0; kc < 3; ++kc) {
    f16x8 af[4], bf[6];
#pragma unroll
    for (int mt = 0; mt < 4; ++mt)
      af[mt] = *(const f16x8*)&vA[(w * 64 + mt * 16 + lm) * 104 + kc * 32 + lq * 8];
#pragma unroll
    for (int nt = 0; nt < 6; ++nt)
      bf[nt] = *(const f16x8*)&ccB[(nt * 16 + lm) * 104 + kc * 32 + lq * 8];
#pragma unroll
    for (int mt = 0; mt < 4; ++mt)
#pragma unroll
      for (int nt = 0; nt < 6; ++nt)
        acc[mt][nt] = __builtin_amdgcn_mfma_f32_16x16x32_f16(
            af[mt], bf[nt], acc[mt][nt], 0, 0, 0);
  }
#pragma unroll
  for (int mt = 0; mt < 4; ++mt) {
#pragma unroll
    for (int reg = 0; reg < 4; ++reg) {
      int l = w * 64 + mt * 16 + lq * 4 + reg;
      __half* orow = QW + l * 180 + 90;
#pragma unroll
      for (int nt = 0; nt < 6; ++nt) {
        int c = nt * 16 + lm;
        if (c < 90) orow[c] = f2h(acc[mt][nt][reg] * 0.001953125f);  // 2^22 -> 2^13
      }
    }
  }
}

// ---------------------------------------------------------------------------
// K8 (MFMA, no LDS, no barriers): out = (XS/8192) @ proj_w + proj_b, f32 out,
// window-reverse scatter. A-frags straight from XS (f16), B from PWT table.
// ---------------------------------------------------------------------------
__global__ __launch_bounds__(256) void k8_proj(const __half* __restrict__ XS,
                                               const f16* __restrict__ PWT,
                                               const float* __restrict__ PB,
                                               float* __restrict__ OUT) {
  int t = threadIdx.x;
  int w0r = blockIdx.x * 128;
  int lane = t & 63, wave = t >> 6;
  int lm = lane & 15, lq = lane >> 4;

  f16x8 ax[6][2];
#pragma unroll
  for (int mt = 0; mt < 2; ++mt) {
    int row = w0r + wave * 32 + mt * 16 + lm;
    const f16* xr = (const f16*)XS + (size_t)row * 180;
#pragma unroll
    for (int ch = 0; ch < 6; ++ch) {
      int k0 = ch * 32 + lq * 8;
      U8 v; v.u4 = (uint4){0u, 0u, 0u, 0u};
      if (k0 + 8 <= 180) {
        v.u2[0] = *(const uint2*)&xr[k0];
        v.u2[1] = *(const uint2*)&xr[k0 + 4];
      } else if (k0 < 180) {  // k0 == 176
        v.u2[0] = *(const uint2*)&xr[k0];
      }
      ax[ch][mt] = v.v;
    }
  }

  for (int bn = 0; bn < 4; ++bn) {
    int n0 = bn * 48;
    f32x4 acc[2][3];
#pragma unroll
    for (int i = 0; i < 2; ++i)
#pragma unroll
      for (int j = 0; j < 3; ++j) acc[i][j] = (f32x4){0.f, 0.f, 0.f, 0.f};

#pragma unroll
    for (int ch = 0; ch < 6; ++ch) {
#pragma unroll
      for (int nt = 0; nt < 3; ++nt) {
        int n = n0 + nt * 16 + lm;
        f16x8 bf = *(const f16x8*)&PWT[n * 192 + ch * 32 + lq * 8];
        acc[0][nt] = __builtin_amdgcn_mfma_f32_16x16x32_f16(
            ax[ch][0], bf, acc[0][nt], 0, 0, 0);
        acc[1][nt] = __builtin_amdgcn_mfma_f32_16x16x32_f16(
            ax[ch][1], bf, acc[1][nt], 0, 0, 0);
      }
    }

    float pb[3];
#pragma unroll
    for (int nt = 0; nt < 3; ++nt) {
      int col = n0 + nt * 16 + lm;
      pb[nt] = (col < 180) ? PB[col] : 0.f;
    }
    const float inv = 1.0f / 8192.0f;
#pragma unroll
    for (int mt = 0; mt < 2; ++mt) {
#pragma unroll
      for (int reg = 0; reg < 4; ++reg) {
        int w = w0r + wave * 32 + mt * 16 + lq * 4 + reg;
        int wi = w >> 8, l = w & 255;
        int b = wi >> 8, wy = (wi >> 4) & 15, wx = wi & 15;
        int ly = l >> 4, lx = l & 15;
        int p = (b << 16) | (((wy << 4) | ly) << 8) | ((wx << 4) | lx);
        float* orow = OUT + (size_t)p * 180;
#pragma unroll
        for (int nt = 0; nt < 3; ++nt) {
          int col = n0 + nt * 16 + lm;
          if (col < 180) orow[col] = acc[mt][nt][reg] * inv + pb[nt];
        }
      }
    }
  }
}

// ---------------------------------------------------------------------------
// Workspace layout (bytes) — peak requirement 66,060,288 (63.0 MB):
//  W2T f16 [9][48][40]      @ 0            (34,560)  written k0_w2 (pre-k1),
//                                                    dead after k2; QX
//                                                    overwrites (k3)
//  QX  f16 [512][256][180]  @ 0            (47,185,920)  qv*64 -> XS in place
//  T1  f16 [131072][36]     @ 47,185,920   ( 9,437,184)  dead after k2
//  T2  f16 [131072][36]     @ 56,623,104   ( 9,437,184)  dead after k3
//  PTAB f32 [961*6]         @ 47,185,920   over dead T1
//  RPB  f32 [6][256][64]    @ 47,212,544   over dead T1 (ends 47,605,760)
//  WT3  f16 [192][40]       @ 47,605,760   (15,360)  written k0_wt (post-k2)
//  WTD  f16 [192][192]      @ 47,621,120   (73,728)  dead after k3; CC
//                                                    overwrites both (k7a)
//  CC   f32 [512][90][90]   @ 47,605,760   (16,588,800, ends 64,194,560)
//  PWT  f16 [192][192]      @ 64,194,560   (73,728)  written k0_pw (post-k3)
// ---------------------------------------------------------------------------
extern "C" void kernel_launch(void* const* d_in, const int* in_sizes, int n_in,
                              void* d_out, int out_size, void* d_ws, size_t ws_size,
                              hipStream_t stream) {
  const float* X    = (const float*)d_in[0];
  const float* W1   = (const float*)d_in[1];
  const float* B1   = (const float*)d_in[2];
  const float* W2   = (const float*)d_in[3];
  const float* B2   = (const float*)d_in[4];
  const float* W3   = (const float*)d_in[5];
  const float* B3c  = (const float*)d_in[6];
  const float* WD   = (const float*)d_in[7];
  const float* BD   = (const float*)d_in[8];
  const float* SLW  = (const float*)d_in[9];
  const float* SLB  = (const float*)d_in[10];
  const float* PPW  = (const float*)d_in[11];
  const float* PPB  = (const float*)d_in[12];
  const float* LN1G = (const float*)d_in[13];
  const float* LN1B = (const float*)d_in[14];
  const float* M1W  = (const float*)d_in[15];
  const float* M1B  = (const float*)d_in[16];
  const float* LN2G = (const float*)d_in[17];
  const float* LN2B = (const float*)d_in[18];
  const float* M2W  = (const float*)d_in[19];
  const float* M2B  = (const float*)d_in[20];
  const float* LN3G = (const float*)d_in[21];
  const float* LN3B = (const float*)d_in[22];
  const float* M3W  = (const float*)d_in[23];
  const float* M3B  = (const float*)d_in[24];
  const float* PW   = (const float*)d_in[25];
  const float* PB   = (const float*)d_in[26];
  float* OUT = (float*)d_out;

  char* ws = (char*)d_ws;
  f16*   W2T  = (f16*)(ws);
  __half* QX  = (__half*)(ws);
  __half* T1  = (__half*)(ws + 47185920);
  __half* T2  = (__half*)(ws + 56623104);
  float* PTAB = (float*)(ws + 47185920);
  float* RPB  = (float*)(ws + 47212544);
  f16*   WT3  = (f16*)(ws + 47605760);
  f16*   WTD  = (f16*)(ws + 47621120);
  float* CC   = (float*)(ws + 47605760);
  f16*   PWT  = (f16*)(ws + 64194560);

  hipLaunchKernelGGL(k0_w2, dim3(68), dim3(256), 0, stream, W2, W2T);
  hipLaunchKernelGGL(k1_conv1, dim3(1024), dim3(256), 0, stream, X, W1, B1, T1);
  hipLaunchKernelGGL(k2_conv2, dim3(1024), dim3(256), 0, stream, T1, W2T, B2, T2);
  hipLaunchKernelGGL(k0_wt, dim3(144), dim3(256), 0, stream, W3, WD, WT3, WTD);
  hipLaunchKernelGGL(k3_qv, dim3(1024), dim3(256), 0, stream, X, T2, WT3, WTD, B3c, BD, QX);
  hipLaunchKernelGGL(k0_pw, dim3(144), dim3(256), 0, stream, PW, PWT);
  hipLaunchKernelGGL(k5a_posmlp, dim3(4), dim3(256), 0, stream,
                     PPW, PPB, LN1G, LN1B, M1W, M1B, LN2G, LN2B, M2W, M2B,
                     LN3G, LN3B, M3W, M3B, PTAB);
  hipLaunchKernelGGL(k5b_rpb, dim3(384), dim3(256), 0, stream, PTAB, RPB);
  hipLaunchKernelGGL(k7a_cc, dim3(512), dim3(256), 0, stream, QX, CC);
  hipLaunchKernelGGL(kA_xsp, dim3(512), dim3(256), 0, stream, QX, RPB, SLW, SLB);
  hipLaunchKernelGGL(kB_xch, dim3(512), dim3(256), 0, stream, QX, CC);
  hipLaunchKernelGGL(k8_proj, dim3(1024), dim3(256), 0, stream, QX, PWT, PB, OUT);
}

// Round 7
// 522.182 us; speedup vs baseline: 1.5362x; 1.0380x over previous
//
#include <hip/hip_runtime.h>
#include <hip/hip_fp16.h>

typedef unsigned int uint32;
typedef _Float16 f16;
typedef f16 f16x4 __attribute__((ext_vector_type(4)));
typedef f16 f16x8 __attribute__((ext_vector_type(8)));
typedef float f32x4 __attribute__((ext_vector_type(4)));

union U8 { f16x8 v; uint4 u4; uint2 u2[2]; f16 h[8]; };

__device__ __forceinline__ float h2f(__half v) { return __half2float(v); }
__device__ __forceinline__ __half f2h(float v) { return __float2half(v); }

// ---------------------------------------------------------------------------
// K0_w1: conv1_w -> W1T[48][192] f16, n-major, zero-padded.
// W1T[n*192+k] = W1[k*36+n] for n<36,k<180 else 0. At ws+34560 (QX region).
// ---------------------------------------------------------------------------
__global__ __launch_bounds__(256) void k0_w1(const float* __restrict__ W1,
                                             f16* __restrict__ W1T) {
  int i = blockIdx.x * 256 + threadIdx.x;
  if (i < 9216) {
    int n = i / 192, k = i % 192;
    W1T[i] = (n < 36 && k < 180) ? (f16)W1[k * 36 + n] : (f16)0;
  }
}

// ---------------------------------------------------------------------------
// K1 (MFMA, no LDS, no barriers): t1 = leaky_relu(x @ conv1_w + b1), f16 out.
// A-frags = X rows f32->f16 in registers; B-frags = 16B loads from W1T.
// Grid: 1024 blocks x 256 thr (4 waves, 32 rows/wave). 36 MFMA/wave.
// ---------------------------------------------------------------------------
__global__ __launch_bounds__(256) void k1_conv1(const float* __restrict__ X,
                                                const f16* __restrict__ W1T,
                                                const float* __restrict__ B1,
                                                __half* __restrict__ T1) {
  int t = threadIdx.x;
  int p0 = blockIdx.x * 128;
  int lane = t & 63, wave = t >> 6;
  int lm = lane & 15, lq = lane >> 4;

  f16x8 ax[6][2];
#pragma unroll
  for (int mt = 0; mt < 2; ++mt) {
    int row = p0 + wave * 32 + mt * 16 + lm;
    const float* xr = X + (size_t)row * 180;
#pragma unroll
    for (int ch = 0; ch < 6; ++ch) {
      int k0 = ch * 32 + lq * 8;
      U8 v; v.u4 = (uint4){0u, 0u, 0u, 0u};
      if (k0 + 8 <= 180) {
        float4 a = *(const float4*)&xr[k0];
        float4 b = *(const float4*)&xr[k0 + 4];
        v.h[0]=(f16)a.x; v.h[1]=(f16)a.y; v.h[2]=(f16)a.z; v.h[3]=(f16)a.w;
        v.h[4]=(f16)b.x; v.h[5]=(f16)b.y; v.h[6]=(f16)b.z; v.h[7]=(f16)b.w;
      } else if (k0 < 180) {  // k0 == 176
        float4 a = *(const float4*)&xr[k0];
        v.h[0]=(f16)a.x; v.h[1]=(f16)a.y; v.h[2]=(f16)a.z; v.h[3]=(f16)a.w;
      }
      ax[ch][mt] = v.v;
    }
  }

  f32x4 acc[2][3];
#pragma unroll
  for (int mt = 0; mt < 2; ++mt)
#pragma unroll
    for (int nt = 0; nt < 3; ++nt) acc[mt][nt] = (f32x4){0.f, 0.f, 0.f, 0.f};

#pragma unroll
  for (int ch = 0; ch < 6; ++ch) {
#pragma unroll
    for (int nt = 0; nt < 3; ++nt) {
      int n = nt * 16 + lm;   // < 48, rows >=36 are zeros
      f16x8 bf = *(const f16x8*)&W1T[n * 192 + ch * 32 + lq * 8];
      acc[0][nt] = __builtin_amdgcn_mfma_f32_16x16x32_f16(
          ax[ch][0], bf, acc[0][nt], 0, 0, 0);
      acc[1][nt] = __builtin_amdgcn_mfma_f32_16x16x32_f16(
          ax[ch][1], bf, acc[1][nt], 0, 0, 0);
    }
  }

  float bb[3];
#pragma unroll
  for (int nt = 0; nt < 3; ++nt) {
    int co = nt * 16 + lm;
    bb[nt] = (co < 36) ? B1[co] : 0.f;
  }
#pragma unroll
  for (int mt = 0; mt < 2; ++mt) {
#pragma unroll
    for (int reg = 0; reg < 4; ++reg) {
      int p = p0 + wave * 32 + mt * 16 + lq * 4 + reg;
      __half* o = T1 + (size_t)p * 36;
#pragma unroll
      for (int nt = 0; nt < 3; ++nt) {
        int co = nt * 16 + lm;
        if (co < 36) {
          float v = acc[mt][nt][reg] + bb[nt];
          o[co] = f2h(v > 0.f ? v : 0.2f * v);
        }
      }
    }
  }
}

// ---------------------------------------------------------------------------
// K0_w2: conv2_w -> W2T[9][48][40] f16, n-major per tap, zero-padded.
// ---------------------------------------------------------------------------
__global__ __launch_bounds__(256) void k0_w2(const float* __restrict__ W2,
                                             f16* __restrict__ W2T) {
  int i = blockIdx.x * 256 + threadIdx.x;
  if (i < 17280) {
    int tap = i / 1920, rem = i % 1920, n = rem / 40, k = rem % 40;
    W2T[i] = (n < 36 && k < 36) ? (f16)W2[(tap * 36 + k) * 36 + n] : (f16)0;
  }
}

// ---------------------------------------------------------------------------
// K2 (MFMA implicit GEMM): t2 = leaky_relu(conv3x3(t1)+b2). Block = 128-px
// row strip; ins[3][132][40] f16 staged once (one barrier); per tap (kh,kw)
// A-frag = shifted ins row, B-frag = 16B load from L2-resident W2T.
// ---------------------------------------------------------------------------
__global__ __launch_bounds__(256) void k2_conv2(const __half* __restrict__ T1,
                                                const f16* __restrict__ W2T,
                                                const float* __restrict__ B2,
                                                __half* __restrict__ T2) {
  __shared__ __align__(16) f16 ins[3 * 132 * 40];  // [kh][xx][ci40]
  int t = threadIdx.x;
  int p0 = blockIdx.x * 128;
  int b = p0 >> 16, y = (p0 >> 8) & 255, x0 = p0 & 255;

  const uint32* T1u = (const uint32*)T1;   // rows are 18 u32
  uint32* insu = (uint32*)ins;             // [kh][xx][20 u32]
  for (int i = t; i < 7920; i += 256) {    // 3*132*20
    int kh = i / 2640, rem = i % 2640;
    int xx = rem / 20, u = rem % 20;
    int ry = y + kh - 1, gx = x0 + xx - 1;
    uint32 v = 0u;
    if (u < 18 && xx < 130 && (unsigned)ry < 256u && (unsigned)gx < 256u)
      v = T1u[((size_t)((b * 256 + ry) * 256 + gx)) * 18 + u];
    insu[i] = v;                           // i == (kh*132+xx)*20+u
  }
  __syncthreads();

  int lane = t & 63, wave = t >> 6;
  int lm = lane & 15, lq = lane >> 4;
  const f16x8 zero8 = {(f16)0,(f16)0,(f16)0,(f16)0,(f16)0,(f16)0,(f16)0,(f16)0};

  f32x4 acc[2][3];
#pragma unroll
  for (int mt = 0; mt < 2; ++mt)
#pragma unroll
    for (int nt = 0; nt < 3; ++nt) acc[mt][nt] = (f32x4){0.f, 0.f, 0.f, 0.f};

#pragma unroll
  for (int kh = 0; kh < 3; ++kh) {
#pragma unroll
    for (int kw = 0; kw < 3; ++kw) {
      int tap = kh * 3 + kw;
      f16x8 a0[2], a1[2];
#pragma unroll
      for (int mt = 0; mt < 2; ++mt) {
        int xx = wave * 32 + mt * 16 + lm + kw;   // <= 129
        const f16* ar = &ins[(kh * 132 + xx) * 40];
        a0[mt] = *(const f16x8*)&ar[lq * 8];
        a1[mt] = (lq == 0) ? *(const f16x8*)&ar[32] : zero8;
      }
#pragma unroll
      for (int nt = 0; nt < 3; ++nt) {
        const f16* br = &W2T[(tap * 48 + nt * 16 + lm) * 40];
        f16x8 b0 = *(const f16x8*)&br[lq * 8];
        f16x8 b1 = (lq == 0) ? *(const f16x8*)&br[32] : zero8;
#pragma unroll
        for (int mt = 0; mt < 2; ++mt) {
          acc[mt][nt] = __builtin_amdgcn_mfma_f32_16x16x32_f16(
              a0[mt], b0, acc[mt][nt], 0, 0, 0);
          acc[mt][nt] = __builtin_amdgcn_mfma_f32_16x16x32_f16(
              a1[mt], b1, acc[mt][nt], 0, 0, 0);
        }
      }
    }
  }

  float bb[3];
#pragma unroll
  for (int nt = 0; nt < 3; ++nt) {
    int co = nt * 16 + lm;
    bb[nt] = (co < 36) ? B2[co] : 0.f;
  }
#pragma unroll
  for (int mt = 0; mt < 2; ++mt) {
#pragma unroll
    for (int reg = 0; reg < 4; ++reg) {
      int p = p0 + wave * 32 + mt * 16 + lq * 4 + reg;
      __half* o = T2 + (size_t)p * 36;
#pragma unroll
      for (int nt = 0; nt < 3; ++nt) {
        int co = nt * 16 + lm;
        if (co < 36) {
          float v = acc[mt][nt][reg] + bb[nt];
          o[co] = f2h(v > 0.f ? v : 0.2f * v);
        }
      }
    }
  }
}

// ---------------------------------------------------------------------------
// K0_wt: transpose+convert W3/WD to n-major f16 tables with zero padding.
// ---------------------------------------------------------------------------
__global__ __launch_bounds__(256) void k0_wt(const float* __restrict__ SW3,
                                             const float* __restrict__ SWD,
                                             f16* __restrict__ WT3,
                                             f16* __restrict__ WTD) {
  int tid = blockIdx.x * 256 + threadIdx.x;
  int stride = gridDim.x * 256;
  for (int i = tid; i < 192 * 40; i += stride) {
    int n = i / 40, k = i % 40;
    WT3[i] = (n < 180 && k < 36) ? (f16)SW3[k * 180 + n] : (f16)0;
  }
  for (int i = tid; i < 192 * 192; i += stride) {
    int n = i / 192, k = i % 192;
    WTD[i] = (n < 180 && k < 180) ? (f16)SWD[k * 180 + n] : (f16)0;
  }
}

// K0_pw: same for proj_w -> PWT[192][192]. Launched AFTER k3 (lives over T2).
__global__ __launch_bounds__(256) void k0_pw(const float* __restrict__ SPW,
                                             f16* __restrict__ PWT) {
  int tid = blockIdx.x * 256 + threadIdx.x;
  int stride = gridDim.x * 256;
  for (int i = tid; i < 192 * 192; i += stride) {
    int n = i / 192, k = i % 192;
    PWT[i] = (n < 180 && k < 180) ? (f16)SPW[k * 180 + n] : (f16)0;
  }
}

// ---------------------------------------------------------------------------
// K3 (MFMA, no LDS, no barriers): qv = (t2@W3+b3)*(x@WD+bd), x64 f16,
// windowed scatter. A-frags in registers; B-frags from L2 tables.
// ---------------------------------------------------------------------------
__global__ __launch_bounds__(256) void k3_qv(const float* __restrict__ X,
                                             const __half* __restrict__ T2,
                                             const f16* __restrict__ WT3,
                                             const f16* __restrict__ WTD,
                                             const float* __restrict__ B3,
                                             const float* __restrict__ BD,
                                             __half* __restrict__ QX) {
  int t = threadIdx.x;
  int p0 = blockIdx.x * 128;
  int lane = t & 63, wave = t >> 6;
  int lm = lane & 15, lq = lane >> 4;

  const f16x8 zero8 = {(f16)0,(f16)0,(f16)0,(f16)0,(f16)0,(f16)0,(f16)0,(f16)0};

  f16x8 ax[6][2];
  f16x8 at0[2];
  f16x8 at1[2];
#pragma unroll
  for (int mt = 0; mt < 2; ++mt) {
    int row = p0 + wave * 32 + mt * 16 + lm;
    const float* xr = X + (size_t)row * 180;
#pragma unroll
    for (int ch = 0; ch < 6; ++ch) {
      int k0 = ch * 32 + lq * 8;
      U8 v; v.u4 = (uint4){0u, 0u, 0u, 0u};
      if (k0 + 8 <= 180) {
        float4 a = *(const float4*)&xr[k0];
        float4 b = *(const float4*)&xr[k0 + 4];
        v.h[0]=(f16)a.x; v.h[1]=(f16)a.y; v.h[2]=(f16)a.z; v.h[3]=(f16)a.w;
        v.h[4]=(f16)b.x; v.h[5]=(f16)b.y; v.h[6]=(f16)b.z; v.h[7]=(f16)b.w;
      } else if (k0 < 180) {  // k0 == 176
        float4 a = *(const float4*)&xr[k0];
        v.h[0]=(f16)a.x; v.h[1]=(f16)a.y; v.h[2]=(f16)a.z; v.h[3]=(f16)a.w;
      }
      ax[ch][mt] = v.v;
    }
    const f16* tr = (const f16*)T2 + (size_t)row * 36;
    U8 tv;
    tv.u2[0] = *(const uint2*)&tr[lq * 8];
    tv.u2[1] = *(const uint2*)&tr[lq * 8 + 4];
    at0[mt] = tv.v;
    U8 t1v; t1v.u4 = (uint4){0u, 0u, 0u, 0u};
    if (lq == 0) t1v.u2[0] = *(const uint2*)&tr[32];
    at1[mt] = t1v.v;
  }

  for (int bn = 0; bn < 4; ++bn) {
    int n0 = bn * 48;
    f32x4 accC[2][3], accD[2][3];
#pragma unroll
    for (int i = 0; i < 2; ++i)
#pragma unroll
      for (int j = 0; j < 3; ++j) {
        accC[i][j] = (f32x4){0.f, 0.f, 0.f, 0.f};
        accD[i][j] = (f32x4){0.f, 0.f, 0.f, 0.f};
      }

#pragma unroll
    for (int nt = 0; nt < 3; ++nt) {
      int n = n0 + nt * 16 + lm;
      f16x8 b0 = *(const f16x8*)&WT3[n * 40 + lq * 8];
      f16x8 b1 = (lq == 0) ? *(const f16x8*)&WT3[n * 40 + 32] : zero8;
#pragma unroll
      for (int mt = 0; mt < 2; ++mt) {
        accC[mt][nt] = __builtin_amdgcn_mfma_f32_16x16x32_f16(
            at0[mt], b0, accC[mt][nt], 0, 0, 0);
        accC[mt][nt] = __builtin_amdgcn_mfma_f32_16x16x32_f16(
            at1[mt], b1, accC[mt][nt], 0, 0, 0);
      }
    }

#pragma unroll
    for (int ch = 0; ch < 6; ++ch) {
#pragma unroll
      for (int nt = 0; nt < 3; ++nt) {
        int n = n0 + nt * 16 + lm;
        f16x8 bf = *(const f16x8*)&WTD[n * 192 + ch * 32 + lq * 8];
        accD[0][nt] = __builtin_amdgcn_mfma_f32_16x16x32_f16(
            ax[ch][0], bf, accD[0][nt], 0, 0, 0);
        accD[1][nt] = __builtin_amdgcn_mfma_f32_16x16x32_f16(
            ax[ch][1], bf, accD[1][nt], 0, 0, 0);
      }
    }

    float cb[3], db[3];
#pragma unroll
    for (int nt = 0; nt < 3; ++nt) {
      int col = n0 + nt * 16 + lm;
      cb[nt] = (col < 180) ? B3[col] : 0.f;
      db[nt] = (col < 180) ? BD[col] : 0.f;
    }
#pragma unroll
    for (int mt = 0; mt < 2; ++mt) {
#pragma unroll
      for (int reg = 0; reg < 4; ++reg) {
        int p = p0 + wave * 32 + mt * 16 + lq * 4 + reg;
        int b = p >> 16, y = (p >> 8) & 255, x = p & 255;
        int wi = (b << 8) | ((y >> 4) << 4) | (x >> 4);
        int l = ((y & 15) << 4) | (x & 15);
        __half* orow = QX + ((size_t)(wi * 256 + l)) * 180;
#pragma unroll
        for (int nt = 0; nt < 3; ++nt) {
          int col = n0 + nt * 16 + lm;
          if (col < 180)
            orow[col] = f2h((accC[mt][nt][reg] + cb[nt]) *
                            (accD[mt][nt][reg] + db[nt]) * 64.f);
        }
      }
    }
  }
}

// ---------------------------------------------------------------------------
// K5a: position-bias MLP over 961 grid points -> PTAB[961][6] f32
// ---------------------------------------------------------------------------
__device__ __forceinline__ void ln_relu11(const float* p, const float* g,
                                          const float* b, float* r) {
  float m = 0.f;
#pragma unroll
  for (int j = 0; j < 11; ++j) m += p[j];
  m *= (1.0f / 11.0f);
  float v = 0.f;
#pragma unroll
  for (int j = 0; j < 11; ++j) { float d = p[j] - m; v += d * d; }
  v *= (1.0f / 11.0f);
  float inv = 1.0f / sqrtf(v + 1e-5f);
#pragma unroll
  for (int j = 0; j < 11; ++j) {
    float xn = (p[j] - m) * inv * g[j] + b[j];
    r[j] = fmaxf(xn, 0.f);
  }
}
__device__ __forceinline__ void mm11(const float* r, const float* W,
                                     const float* b, float* o) {
#pragma unroll
  for (int j2 = 0; j2 < 11; ++j2) {
    float s = b[j2];
#pragma unroll
    for (int j = 0; j < 11; ++j) s += r[j] * W[j * 11 + j2];
    o[j2] = s;
  }
}

__global__ __launch_bounds__(256) void k5a_posmlp(
    const float* PPW, const float* PPB,
    const float* LN1G, const float* LN1B, const float* M1W, const float* M1B,
    const float* LN2G, const float* LN2B, const float* M2W, const float* M2B,
    const float* LN3G, const float* LN3B, const float* M3W, const float* M3B,
    float* __restrict__ PTAB) {
  int t = blockIdx.x * 256 + threadIdx.x;
  if (t >= 961) return;
  float g0 = (float)(t / 31) - 15.0f;
  float g1 = (float)(t % 31) - 15.0f;
  float p[11], r[11];
#pragma unroll
  for (int j = 0; j < 11; ++j)
    p[j] = g0 * PPW[j] + g1 * PPW[11 + j] + PPB[j];
  ln_relu11(p, LN1G, LN1B, r);
  mm11(r, M1W, M1B, p);
  ln_relu11(p, LN2G, LN2B, r);
  mm11(r, M2W, M2B, p);
  ln_relu11(p, LN3G, LN3B, r);
#pragma unroll
  for (int h = 0; h < 6; ++h) {
    float s = M3B[h];
#pragma unroll
    for (int j = 0; j < 11; ++j) s += r[j] * M3W[j * 6 + h];
    PTAB[t * 6 + h] = s;
  }
}

// ---------------------------------------------------------------------------
// K5b: RPB[h][l][m] = mean over 2x2 of PTAB[(dr+15)*31+(dc+15)][h]
// ---------------------------------------------------------------------------
__global__ __launch_bounds__(256) void k5b_rpb(const float* __restrict__ PTAB,
                                               float* __restrict__ RPB) {
  int t = blockIdx.x * 256 + threadIdx.x;  // < 98304
  int m = t & 63;
  int l = (t >> 6) & 255;
  int h = t >> 14;
  int mh = m >> 3, mw = m & 7;
  int qr = l >> 4, qc = l & 15;
  float s = 0.f;
#pragma unroll
  for (int rh = 0; rh < 2; ++rh)
#pragma unroll
    for (int rw = 0; rw < 2; ++rw) {
      int dr = qr - (mh * 2 + rh) + 15;
      int dc = qc - (mw * 2 + rw) + 15;
      s += PTAB[(dr * 31 + dc) * 6 + h];
    }
  RPB[t] = 0.25f * s;
}

// ---------------------------------------------------------------------------
// K7a: cc[wi][c][d] = sum_l q[l][c]*v[l][d] / 256, f32 out (true scale).
// ---------------------------------------------------------------------------
__global__ __launch_bounds__(256) void k7a_cc(const __half* __restrict__ QX,
                                              float* __restrict__ CC) {
  __shared__ __half qs[64 * 90];
  __shared__ __half vs[64 * 90];
  int wi = blockIdx.x, t = threadIdx.x;
  int c0 = (t % 15) * 6, d0 = (t / 15) * 6;
  bool act = t < 225;
  float acc[36];
#pragma unroll
  for (int i = 0; i < 36; ++i) acc[i] = 0.f;
  const uint32* G = (const uint32*)(QX + (size_t)wi * 46080);
  uint32* qsw = (uint32*)qs;
  uint32* vsw = (uint32*)vs;
  for (int pass = 0; pass < 4; ++pass) {
    __syncthreads();
    for (int i = t; i < 2880; i += 256) {
      int l = i / 45, k = i % 45;
      int gw = (pass * 64 + l) * 90;
      qsw[l * 45 + k] = G[gw + k];
      vsw[l * 45 + k] = G[gw + 45 + k];
    }
    __syncthreads();
    if (act) {
      for (int l = 0; l < 64; ++l) {
        const __half2* qh = (const __half2*)&qs[l * 90 + c0];
        const __half2* vh = (const __half2*)&vs[l * 90 + d0];
        float a[6], b[6];
#pragma unroll
        for (int k = 0; k < 3; ++k) {
          __half2 x = qh[k];
          a[2 * k] = __low2float(x); a[2 * k + 1] = __high2float(x);
          __half2 y = vh[k];
          b[2 * k] = __low2float(y); b[2 * k + 1] = __high2float(y);
        }
#pragma unroll
        for (int i = 0; i < 6; ++i)
#pragma unroll
          for (int j = 0; j < 6; ++j) acc[i * 6 + j] += a[i] * b[j];
      }
    }
  }
  if (act) {
    const float s = 1.0f / (256.0f * 4096.0f);
#pragma unroll
    for (int i = 0; i < 6; ++i)
#pragma unroll
      for (int j = 0; j < 6; ++j)
        CC[((size_t)(wi * 90 + c0 + i)) * 90 + d0 + j] = acc[i * 6 + j] * s;
  }
}

// ---------------------------------------------------------------------------
// KA (MFMA): per window, per head h:
//   corr^T(64x256) = vp(64x16) x q^T      [mfma_f32_16x16x16f16]
//   corr' = (corr^T * 1/960 + 256*rpb) -> f16 (B-frag layout = C layout!)
//   x_sp^T(16x256) = vpT(16x64) x corr'   [chained over 4 k-tiles]
// x_sp written in place over q-channels as 8192*x_sp (f16).
// ---------------------------------------------------------------------------
__global__ __launch_bounds__(256) void kA_xsp(__half* __restrict__ QX,
                                              const float* __restrict__ RPB,
                                              const float* __restrict__ SLW,
                                              const float* __restrict__ SLB) {
  __shared__ __align__(16) unsigned char SM[80384];
  f16* U   = (f16*)SM;                    // A: v [256][90]; B: qP [256][104]
  f16* vpS = (f16*)(SM + 53248);          // [64][104] m-major (A1 frags)
  f16* vpT = (f16*)(SM + 66560);          // [96][72]  c-major (A2 frags)
  int wi = blockIdx.x, t = threadIdx.x;
  __half* QW = QX + (size_t)wi * 46080;
  const uint32* G = (const uint32*)QW;
  uint32* Uw = (uint32*)U;

  for (int i = t; i < 11520; i += 256) {
    int l = i / 45, k = i % 45;
    Uw[l * 45 + k] = G[l * 90 + 45 + k];
  }
  __syncthreads();
  float w0 = SLW[0], w1 = SLW[1], w2 = SLW[2], w3 = SLW[3];
  float sb = SLB[0];
  for (int e = t; e < 6144; e += 256) {
    int m = e & 63, idx = e >> 6;          // idx = h*16 + c
    int c = idx & 15, h = idx >> 4;
    f16 val = (f16)0;
    if (c < 15) {
      int ch = h * 15 + c;
      int lb = (m >> 3) * 32 + (m & 7) * 2;
      float s = w0 * (float)U[lb * 90 + ch] + w1 * (float)U[(lb + 1) * 90 + ch]
              + w2 * (float)U[(lb + 16) * 90 + ch] + w3 * (float)U[(lb + 17) * 90 + ch];
      val = (f16)(s * 4.f + sb * 256.f);
    }
    vpS[m * 104 + idx] = val;
    vpT[idx * 72 + m] = val;
  }
  __syncthreads();
  for (int j = t; j < 1536; j += 256) {
    int h = j >> 8, l = j & 255;
    U[l * 104 + h * 16 + 15] = (f16)0;
  }
  for (int i = t; i < 11520; i += 256) {
    int l = i / 45, k = i % 45;
    union { uint32 w; f16 h[2]; } cv;
    cv.w = G[l * 90 + k];
    int cg0 = 2 * k, cg1 = 2 * k + 1;
    int h0 = cg0 / 15, c0 = cg0 - h0 * 15;
    int h1 = cg1 / 15, c1 = cg1 - h1 * 15;
    U[l * 104 + h0 * 16 + c0] = cv.h[0];
    U[l * 104 + h1 * 16 + c1] = cv.h[1];
  }
  __syncthreads();

  int lane = t & 63, w = t >> 6;
  int lm = lane & 15, lq = lane >> 4;
  const float invA = 1.0f / 960.0f;        // 256 / (15*16384)
  for (int h = 0; h < 6; ++h) {
    f16x4 a1[4], b1[4];
#pragma unroll
    for (int mt = 0; mt < 4; ++mt)
      a1[mt] = *(const f16x4*)&vpS[(mt * 16 + lm) * 104 + h * 16 + lq * 4];
#pragma unroll
    for (int lt = 0; lt < 4; ++lt)
      b1[lt] = *(const f16x4*)&U[(w * 64 + lt * 16 + lm) * 104 + h * 16 + lq * 4];
    f32x4 acc1[4][4];
#pragma unroll
    for (int mt = 0; mt < 4; ++mt)
#pragma unroll
      for (int lt = 0; lt < 4; ++lt)
        acc1[mt][lt] = __builtin_amdgcn_mfma_f32_16x16x16f16(
            a1[mt], b1[lt], (f32x4){0.f, 0.f, 0.f, 0.f}, 0, 0, 0);
    f16x4 b2[4][4];
#pragma unroll
    for (int lt = 0; lt < 4; ++lt) {
      int l = w * 64 + lt * 16 + lm;
      const float* rp = RPB + ((size_t)(h * 256 + l)) * 64;
#pragma unroll
      for (int mt = 0; mt < 4; ++mt) {
        float4 rv = *(const float4*)&rp[mt * 16 + lq * 4];
        f16x4 bb;
        bb[0] = (f16)(acc1[mt][lt][0] * invA + rv.x * 256.f);
        bb[1] = (f16)(acc1[mt][lt][1] * invA + rv.y * 256.f);
        bb[2] = (f16)(acc1[mt][lt][2] * invA + rv.z * 256.f);
        bb[3] = (f16)(acc1[mt][lt][3] * invA + rv.w * 256.f);
        b2[mt][lt] = bb;
      }
    }
    f16x4 a2[4];
#pragma unroll
    for (int kt = 0; kt < 4; ++kt)
      a2[kt] = *(const f16x4*)&vpT[(h * 16 + lm) * 72 + kt * 16 + lq * 4];
#pragma unroll
    for (int lt = 0; lt < 4; ++lt) {
      f32x4 acc2 = (f32x4){0.f, 0.f, 0.f, 0.f};
#pragma unroll
      for (int kt = 0; kt < 4; ++kt)
        acc2 = __builtin_amdgcn_mfma_f32_16x16x16f16(a2[kt], b2[kt][lt], acc2, 0, 0, 0);
      int l = w * 64 + lt * 16 + lm;
      __half* orow = QW + l * 180 + h * 15;
#pragma unroll
      for (int reg = 0; reg < 4; ++reg) {
        int c = lq * 4 + reg;
        if (c < 15) orow[c] = f2h(acc2[reg] * 0.125f);   // 65536*x_sp / 8
      }
    }
  }
}

// ---------------------------------------------------------------------------
// KB (MFMA): x_ch[l][c] = sum_d cc[c][d]*v[l][d], in place over v-channels
// as 8192*x_ch (f16).
// ---------------------------------------------------------------------------
__global__ __launch_bounds__(256) void kB_xch(__half* __restrict__ QX,
                                              const float* __restrict__ CC) {
  __shared__ __align__(16) f16 vA[256 * 104];
  __shared__ __align__(16) f16 ccB[96 * 104];
  int wi = blockIdx.x, t = threadIdx.x;
  __half* QW = QX + (size_t)wi * 46080;
  const uint32* G = (const uint32*)QW;
  uint32* vAw = (uint32*)vA;
  for (int i = t; i < 12288; i += 256) {   // 256 rows x 48 u32 (cols 0..95)
    int l = i / 48, kk = i % 48;
    vAw[l * 52 + kk] = (kk < 45) ? G[l * 90 + 45 + kk] : 0u;
  }
  const float* ccg = CC + (size_t)wi * 8100;
  uint32* ccw = (uint32*)ccB;
  for (int i = t; i < 4992; i += 256) {    // 96 rows x 52 u32, zero pads
    int c = i / 52, dd = i % 52;
    uint32 out = 0u;
    if (c < 90 && dd < 45) {
      float2 f = *(const float2*)&ccg[c * 90 + dd * 2];
      union { uint32 w; f16 h[2]; } cv;
      cv.h[0] = (f16)(f.x * 65536.f);
      cv.h[1] = (f16)(f.y * 65536.f);
      out = cv.w;
    }
    ccw[c * 52 + dd] = out;
  }
  __syncthreads();
  int lane = t & 63, w = t >> 6;
  int lm = lane & 15, lq = lane >> 4;
  f32x4 acc[4][6];
#pragma unroll
  for (int mt = 0; mt < 4; ++mt)
#pragma unroll
    for (int nt = 0; nt < 6; ++nt) acc[mt][nt] = (f32x4){0.f, 0.f, 0.f, 0.f};
  for (int kc = 0; kc < 3; ++kc) {
    f16x8 af[4], bf[6];
#pragma unroll
    for (int mt = 0; mt < 4; ++mt)
      af[mt] = *(const f16x8*)&vA[(w * 64 + mt * 16 + lm) * 104 + kc * 32 + lq * 8];
#pragma unroll
    for (int nt = 0; nt < 6; ++nt)
      bf[nt] = *(const f16x8*)&ccB[(nt * 16 + lm) * 104 + kc * 32 + lq * 8];
#pragma unroll
    for (int mt = 0; mt < 4; ++mt)
#pragma unroll
      for (int nt = 0; nt < 6; ++nt)
        acc[mt][nt] = __builtin_amdgcn_mfma_f32_16x16x32_f16(
            af[mt], bf[nt], acc[mt][nt], 0, 0, 0);
  }
#pragma unroll
  for (int mt = 0; mt < 4; ++mt) {
#pragma unroll
    for (int reg = 0; reg < 4; ++reg) {
      int l = w * 64 + mt * 16 + lq * 4 + reg;
      __half* orow = QW + l * 180 + 90;
#pragma unroll
      for (int nt = 0; nt < 6; ++nt) {
        int c = nt * 16 + lm;
        if (c < 90) orow[c] = f2h(acc[mt][nt][reg] * 0.001953125f);  // 2^22 -> 2^13
      }
    }
  }
}

// ---------------------------------------------------------------------------
// K8 (MFMA, no LDS, no barriers): out = (XS/8192) @ proj_w + proj_b, f32 out,
// window-reverse scatter. A-frags straight from XS (f16), B from PWT table.
// ---------------------------------------------------------------------------
__global__ __launch_bounds__(256) void k8_proj(const __half* __restrict__ XS,
                                               const f16* __restrict__ PWT,
                                               const float* __restrict__ PB,
                                               float* __restrict__ OUT) {
  int t = threadIdx.x;
  int w0r = blockIdx.x * 128;
  int lane = t & 63, wave = t >> 6;
  int lm = lane & 15, lq = lane >> 4;

  f16x8 ax[6][2];
#pragma unroll
  for (int mt = 0; mt < 2; ++mt) {
    int row = w0r + wave * 32 + mt * 16 + lm;
    const f16* xr = (const f16*)XS + (size_t)row * 180;
#pragma unroll
    for (int ch = 0; ch < 6; ++ch) {
      int k0 = ch * 32 + lq * 8;
      U8 v; v.u4 = (uint4){0u, 0u, 0u, 0u};
      if (k0 + 8 <= 180) {
        v.u2[0] = *(const uint2*)&xr[k0];
        v.u2[1] = *(const uint2*)&xr[k0 + 4];
      } else if (k0 < 180) {  // k0 == 176
        v.u2[0] = *(const uint2*)&xr[k0];
      }
      ax[ch][mt] = v.v;
    }
  }

  for (int bn = 0; bn < 4; ++bn) {
    int n0 = bn * 48;
    f32x4 acc[2][3];
#pragma unroll
    for (int i = 0; i < 2; ++i)
#pragma unroll
      for (int j = 0; j < 3; ++j) acc[i][j] = (f32x4){0.f, 0.f, 0.f, 0.f};

#pragma unroll
    for (int ch = 0; ch < 6; ++ch) {
#pragma unroll
      for (int nt = 0; nt < 3; ++nt) {
        int n = n0 + nt * 16 + lm;
        f16x8 bf = *(const f16x8*)&PWT[n * 192 + ch * 32 + lq * 8];
        acc[0][nt] = __builtin_amdgcn_mfma_f32_16x16x32_f16(
            ax[ch][0], bf, acc[0][nt], 0, 0, 0);
        acc[1][nt] = __builtin_amdgcn_mfma_f32_16x16x32_f16(
            ax[ch][1], bf, acc[1][nt], 0, 0, 0);
      }
    }

    float pb[3];
#pragma unroll
    for (int nt = 0; nt < 3; ++nt) {
      int col = n0 + nt * 16 + lm;
      pb[nt] = (col < 180) ? PB[col] : 0.f;
    }
    const float inv = 1.0f / 8192.0f;
#pragma unroll
    for (int mt = 0; mt < 2; ++mt) {
#pragma unroll
      for (int reg = 0; reg < 4; ++reg) {
        int w = w0r + wave * 32 + mt * 16 + lq * 4 + reg;
        int wi = w >> 8, l = w & 255;
        int b = wi >> 8, wy = (wi >> 4) & 15, wx = wi & 15;
        int ly = l >> 4, lx = l & 15;
        int p = (b << 16) | (((wy << 4) | ly) << 8) | ((wx << 4) | lx);
        float* orow = OUT + (size_t)p * 180;
#pragma unroll
        for (int nt = 0; nt < 3; ++nt) {
          int col = n0 + nt * 16 + lm;
          if (col < 180) orow[col] = acc[mt][nt][reg] * inv + pb[nt];
        }
      }
    }
  }
}

// ---------------------------------------------------------------------------
// Workspace layout (bytes) — peak requirement 66,060,288 (63.0 MB):
//  W2T f16 [9][48][40]      @ 0            (34,560)  written k0_w2 (pre-k1),
//                                                    dead after k2
//  W1T f16 [48][192]        @ 34,560       (18,432)  written k0_w1 (pre-k1),
//                                                    dead after k1; QX
//                                                    overwrites both (k3)
//  QX  f16 [512][256][180]  @ 0            (47,185,920)  qv*64 -> XS in place
//  T1  f16 [131072][36]     @ 47,185,920   ( 9,437,184)  dead after k2
//  T2  f16 [131072][36]     @ 56,623,104   ( 9,437,184)  dead after k3
//  PTAB f32 [961*6]         @ 47,185,920   over dead T1
//  RPB  f32 [6][256][64]    @ 47,212,544   over dead T1 (ends 47,605,760)
//  WT3  f16 [192][40]       @ 47,605,760   (15,360)  written k0_wt (post-k2)
//  WTD  f16 [192][192]      @ 47,621,120   (73,728)  dead after k3; CC
//                                                    overwrites both (k7a)
//  CC   f32 [512][90][90]   @ 47,605,760   (16,588,800, ends 64,194,560)
//  PWT  f16 [192][192]      @ 64,194,560   (73,728)  written k0_pw (post-k3)
// ---------------------------------------------------------------------------
extern "C" void kernel_launch(void* const* d_in, const int* in_sizes, int n_in,
                              void* d_out, int out_size, void* d_ws, size_t ws_size,
                              hipStream_t stream) {
  const float* X    = (const float*)d_in[0];
  const float* W1   = (const float*)d_in[1];
  const float* B1   = (const float*)d_in[2];
  const float* W2   = (const float*)d_in[3];
  const float* B2   = (const float*)d_in[4];
  const float* W3   = (const float*)d_in[5];
  const float* B3c  = (const float*)d_in[6];
  const float* WD   = (const float*)d_in[7];
  const float* BD   = (const float*)d_in[8];
  const float* SLW  = (const float*)d_in[9];
  const float* SLB  = (const float*)d_in[10];
  const float* PPW  = (const float*)d_in[11];
  const float* PPB  = (const float*)d_in[12];
  const float* LN1G = (const float*)d_in[13];
  const float* LN1B = (const float*)d_in[14];
  const float* M1W  = (const float*)d_in[15];
  const float* M1B  = (const float*)d_in[16];
  const float* LN2G = (const float*)d_in[17];
  const float* LN2B = (const float*)d_in[18];
  const float* M2W  = (const float*)d_in[19];
  const float* M2B  = (const float*)d_in[20];
  const float* LN3G = (const float*)d_in[21];
  const float* LN3B = (const float*)d_in[22];
  const float* M3W  = (const float*)d_in[23];
  const float* M3B  = (const float*)d_in[24];
  const float* PW   = (const float*)d_in[25];
  const float* PB   = (const float*)d_in[26];
  float* OUT = (float*)d_out;

  char* ws = (char*)d_ws;
  f16*   W2T  = (f16*)(ws);
  f16*   W1T  = (f16*)(ws + 34560);
  __half* QX  = (__half*)(ws);
  __half* T1  = (__half*)(ws + 47185920);
  __half* T2  = (__half*)(ws + 56623104);
  float* PTAB = (float*)(ws + 47185920);
  float* RPB  = (float*)(ws + 47212544);
  f16*   WT3  = (f16*)(ws + 47605760);
  f16*   WTD  = (f16*)(ws + 47621120);
  float* CC   = (float*)(ws + 47605760);
  f16*   PWT  = (f16*)(ws + 64194560);

  hipLaunchKernelGGL(k0_w2, dim3(68), dim3(256), 0, stream, W2, W2T);
  hipLaunchKernelGGL(k0_w1, dim3(36), dim3(256), 0, stream, W1, W1T);
  hipLaunchKernelGGL(k1_conv1, dim3(1024), dim3(256), 0, stream, X, W1T, B1, T1);
  hipLaunchKernelGGL(k2_conv2, dim3(1024), dim3(256), 0, stream, T1, W2T, B2, T2);
  hipLaunchKernelGGL(k0_wt, dim3(144), dim3(256), 0, stream, W3, WD, WT3, WTD);
  hipLaunchKernelGGL(k3_qv, dim3(1024), dim3(256), 0, stream, X, T2, WT3, WTD, B3c, BD, QX);
  hipLaunchKernelGGL(k0_pw, dim3(144), dim3(256), 0, stream, PW, PWT);
  hipLaunchKernelGGL(k5a_posmlp, dim3(4), dim3(256), 0, stream,
                     PPW, PPB, LN1G, LN1B, M1W, M1B, LN2G, LN2B, M2W, M2B,
                     LN3G, LN3B, M3W, M3B, PTAB);
  hipLaunchKernelGGL(k5b_rpb, dim3(384), dim3(256), 0, stream, PTAB, RPB);
  hipLaunchKernelGGL(k7a_cc, dim3(512), dim3(256), 0, stream, QX, CC);
  hipLaunchKernelGGL(kA_xsp, dim3(512), dim3(256), 0, stream, QX, RPB, SLW, SLB);
  hipLaunchKernelGGL(kB_xch, dim3(512), dim3(256), 0, stream, QX, CC);
  hipLaunchKernelGGL(k8_proj, dim3(1024), dim3(256), 0, stream, QX, PWT, PB, OUT);
}